// Round 1
// baseline (371.188 us; speedup 1.0000x reference)
//
#include <hip/hip_runtime.h>
#include <math.h>

// ---------------- CSR build ----------------

__global__ void count_k(const int* __restrict__ dst, int* __restrict__ cnt, int E){
  int e = blockIdx.x*blockDim.x + threadIdx.x;
  if(e < E) atomicAdd(&cnt[dst[e]], 1);
}

__global__ void scan1_k(const int* __restrict__ cnt, int* __restrict__ bsum, int n){
  __shared__ int ws[16];
  int i = blockIdx.x*1024 + threadIdx.x;
  int v = (i < n) ? cnt[i] : 0;
  #pragma unroll
  for(int m=1;m<64;m<<=1) v += __shfl_xor(v, m);
  if((threadIdx.x & 63) == 0) ws[threadIdx.x >> 6] = v;
  __syncthreads();
  if(threadIdx.x == 0){
    int s = 0;
    #pragma unroll
    for(int w=0; w<16; w++) s += ws[w];
    bsum[blockIdx.x] = s;
  }
}

__global__ void scan2_k(int* __restrict__ bsum, int nb, int* __restrict__ row_ptr, int n, int E){
  if(threadIdx.x==0 && blockIdx.x==0){
    int s=0;
    for(int b=0;b<nb;b++){ int v=bsum[b]; bsum[b]=s; s+=v; }
    row_ptr[n] = E;
  }
}

__global__ void scan3_k(const int* __restrict__ cnt, const int* __restrict__ bsum,
                        int* __restrict__ row_ptr, int* __restrict__ cursor, int n){
  __shared__ int sm[1024];
  int i = blockIdx.x*1024 + threadIdx.x;
  int v = (i<n)? cnt[i] : 0;
  sm[threadIdx.x] = v;
  __syncthreads();
  for(int off=1; off<1024; off<<=1){
    int t = (threadIdx.x>=off)? sm[threadIdx.x-off] : 0;
    __syncthreads();
    sm[threadIdx.x] += t;
    __syncthreads();
  }
  if(i<n){
    int ex = sm[threadIdx.x] - v + bsum[blockIdx.x];
    row_ptr[i] = ex;
    cursor[i] = ex;
  }
}

__global__ void fill_k(const int* __restrict__ src, const int* __restrict__ dst,
                       int* __restrict__ cursor, int* __restrict__ csr_src, int E){
  int e = blockIdx.x*blockDim.x + threadIdx.x;
  if(e < E){
    int p = atomicAdd(&cursor[dst[e]], 1);
    csr_src[p] = src[e];
  }
}

// ---------------- dense: Y[n][j] = sum_k X[n][k]*W[j][k] + b[j], 128x128 ----------------
// WT staged transposed in LDS (stride 130: even for float2 align, conflict-light).
// 4 waves/block, 2 rows/wave, lane covers cols 2l,2l+1.

__global__ __launch_bounds__(256) void gemm128_k(const float* __restrict__ X,
    const float* __restrict__ W, const float* __restrict__ b,
    float* __restrict__ Y, int nrows){
  __shared__ float WT[128*130];
  __shared__ float XR[8][128];
  int t = threadIdx.x;
  #pragma unroll
  for(int i=0;i<64;i++){
    int idx = t + i*256;
    int j = idx >> 7, k = idx & 127;
    WT[k*130 + j] = W[idx];
  }
  __syncthreads();
  int wid = t >> 6, lane = t & 63;
  float2 bb = *(const float2*)&b[2*lane];
  for(int base = blockIdx.x*8 + wid*2; base < nrows; base += gridDim.x*8){
    bool r1ok = (base+1) < nrows;
    float2 x0 = *(const float2*)&X[(size_t)base*128 + 2*lane];
    float2 x1 = r1ok ? *(const float2*)&X[(size_t)(base+1)*128 + 2*lane] : make_float2(0.f,0.f);
    *(float2*)&XR[wid*2  ][2*lane] = x0;
    *(float2*)&XR[wid*2+1][2*lane] = x1;
    float a00=bb.x, a01=bb.y, a10=bb.x, a11=bb.y;
    #pragma unroll 8
    for(int k=0;k<128;k++){
      float xk0 = XR[wid*2][k];
      float xk1 = XR[wid*2+1][k];
      float2 w2 = *(const float2*)&WT[k*130 + 2*lane];
      a00 += xk0*w2.x; a01 += xk0*w2.y;
      a10 += xk1*w2.x; a11 += xk1*w2.y;
    }
    *(float2*)&Y[(size_t)base*128 + 2*lane] = make_float2(a00,a01);
    if(r1ok) *(float2*)&Y[(size_t)(base+1)*128 + 2*lane] = make_float2(a10,a11);
  }
}

// ---------------- GATv2 edge phase: fused logits + online softmax + aggregate ----------------
// One wave per dst node. Lane l owns channels 2l,2l+1; lanes 0-31 head 0, 32-63 head 1.

__global__ __launch_bounds__(256) void gat_agg_k(const float* __restrict__ XW,
    const float* __restrict__ att, const int* __restrict__ row_ptr,
    const int* __restrict__ csr_src, float* __restrict__ outp, int n){
  int wid = threadIdx.x >> 6, lane = threadIdx.x & 63;
  int node = blockIdx.x*4 + wid;
  if(node >= n) return;
  float2 a  = *(const float2*)&att[2*lane];
  float2 xd = *(const float2*)&XW[(size_t)node*128 + 2*lane];
  int beg = row_ptr[node], end = row_ptr[node+1];
  float m = -INFINITY, s = 0.f, acc0 = 0.f, acc1 = 0.f;
  int i = beg;
  for(; i+1 < end; i += 2){
    int s0 = csr_src[i], s1 = csr_src[i+1];
    float2 xa = *(const float2*)&XW[(size_t)s0*128 + 2*lane];
    float2 xb = *(const float2*)&XW[(size_t)s1*128 + 2*lane];
    float va0=xd.x+xa.x, va1=xd.y+xa.y, vb0=xd.x+xb.x, vb1=xd.y+xb.y;
    va0 = va0>0.f?va0:0.2f*va0;  va1 = va1>0.f?va1:0.2f*va1;
    vb0 = vb0>0.f?vb0:0.2f*vb0;  vb1 = vb1>0.f?vb1:0.2f*vb1;
    float pa = va0*a.x + va1*a.y;
    float pb = vb0*a.x + vb1*a.y;
    #pragma unroll
    for(int mm=1; mm<32; mm<<=1){ pa += __shfl_xor(pa,mm); pb += __shfl_xor(pb,mm); }
    float mn = fmaxf(m, pa);
    float sc = __expf(m - mn);
    float p  = __expf(pa - mn);
    m = mn; s = s*sc + p; acc0 = acc0*sc + p*xa.x; acc1 = acc1*sc + p*xa.y;
    mn = fmaxf(m, pb);
    sc = __expf(m - mn);
    p  = __expf(pb - mn);
    m = mn; s = s*sc + p; acc0 = acc0*sc + p*xb.x; acc1 = acc1*sc + p*xb.y;
  }
  if(i < end){
    int s0 = csr_src[i];
    float2 xa = *(const float2*)&XW[(size_t)s0*128 + 2*lane];
    float v0=xd.x+xa.x, v1=xd.y+xa.y;
    v0 = v0>0.f?v0:0.2f*v0;  v1 = v1>0.f?v1:0.2f*v1;
    float pa = v0*a.x + v1*a.y;
    #pragma unroll
    for(int mm=1; mm<32; mm<<=1) pa += __shfl_xor(pa,mm);
    float mn = fmaxf(m, pa);
    float sc = __expf(m - mn);
    float p  = __expf(pa - mn);
    m = mn; s = s*sc + p; acc0 = acc0*sc + p*xa.x; acc1 = acc1*sc + p*xa.y;
  }
  float inv = (end > beg) ? 1.f/s : 0.f;
  float o0 = fmaxf(acc0*inv, 0.f);
  float o1 = fmaxf(acc1*inv, 0.f);
  *(float2*)&outp[(size_t)node*128 + 2*lane] = make_float2(o0, o1);
}

// ---------------- fused MLP head: sigmoid((H@Wp1^T+bp1)@Wp2^T+bp2) ----------------

__global__ __launch_bounds__(256) void mlp_k(const float* __restrict__ Hin,
    const float* __restrict__ Wp1, const float* __restrict__ bp1,
    const float* __restrict__ Wp2, const float* __restrict__ bp2,
    float* __restrict__ Yout, int nrows){
  __shared__ float WT[128*66];   // WT[k*66+j] = Wp1[j*128+k], j<64
  __shared__ float XR[8][128];
  int t = threadIdx.x;
  #pragma unroll
  for(int i=0;i<32;i++){
    int idx = t + i*256;         // 0..8191
    int j = idx >> 7, k = idx & 127;
    WT[k*66 + j] = Wp1[idx];
  }
  __syncthreads();
  int wid = t >> 6, lane = t & 63;
  float wp2 = Wp2[lane];
  float bb1 = bp1[lane];
  float bb2 = bp2[0];
  for(int base = blockIdx.x*8 + wid*2; base < nrows; base += gridDim.x*8){
    bool r1ok = (base+1) < nrows;
    float2 x0 = *(const float2*)&Hin[(size_t)base*128 + 2*lane];
    float2 x1 = r1ok ? *(const float2*)&Hin[(size_t)(base+1)*128 + 2*lane] : make_float2(0.f,0.f);
    *(float2*)&XR[wid*2  ][2*lane] = x0;
    *(float2*)&XR[wid*2+1][2*lane] = x1;
    float a0 = bb1, a1 = bb1;
    #pragma unroll 8
    for(int k=0;k<128;k++){
      float w = WT[k*66 + lane];
      a0 += XR[wid*2][k]*w;
      a1 += XR[wid*2+1][k]*w;
    }
    float r0 = a0*wp2, r1 = a1*wp2;
    #pragma unroll
    for(int mm=1; mm<64; mm<<=1){ r0 += __shfl_xor(r0,mm); r1 += __shfl_xor(r1,mm); }
    if(lane == 0){
      Yout[base] = 1.f/(1.f + __expf(-(r0 + bb2)));
      if(r1ok) Yout[base+1] = 1.f/(1.f + __expf(-(r1 + bb2)));
    }
  }
}

// ---------------- launcher ----------------

extern "C" void kernel_launch(void* const* d_in, const int* in_sizes, int n_in,
                              void* d_out, int out_size, void* d_ws, size_t ws_size,
                              hipStream_t stream) {
  const float* x    = (const float*)d_in[0];
  const int*   ei   = (const int*)  d_in[1];
  const float* W1   = (const float*)d_in[2];
  const float* b1   = (const float*)d_in[3];
  const float* att1 = (const float*)d_in[4];
  const float* W2   = (const float*)d_in[5];
  const float* b2   = (const float*)d_in[6];
  const float* att2 = (const float*)d_in[7];
  const float* Wp1  = (const float*)d_in[8];
  const float* bp1  = (const float*)d_in[9];
  const float* Wp2  = (const float*)d_in[10];
  const float* bp2  = (const float*)d_in[11];
  float* out = (float*)d_out;

  int N = in_sizes[0] / 128;
  int E = in_sizes[1] / 2;

  char* ws = (char*)d_ws;
  float* bufA   = (float*)ws; ws += (size_t)N*128*sizeof(float);
  float* bufB   = (float*)ws; ws += (size_t)N*128*sizeof(float);
  int* row_ptr  = (int*)ws;   ws += (size_t)(N+1)*sizeof(int);
  int* cursor   = (int*)ws;   ws += (size_t)N*sizeof(int);
  int* cnt      = (int*)ws;   ws += (size_t)N*sizeof(int);
  int* bsum     = (int*)ws;   ws += 64*sizeof(int);
  int* csr_src  = (int*)ws;   ws += (size_t)E*sizeof(int);

  const int* esrc = ei;
  const int* edst = ei + E;

  hipMemsetAsync(cnt, 0, (size_t)N*sizeof(int), stream);

  int nb = (N + 1023) / 1024;
  count_k<<<(E+255)/256, 256, 0, stream>>>(edst, cnt, E);
  scan1_k<<<nb, 1024, 0, stream>>>(cnt, bsum, N);
  scan2_k<<<1, 64, 0, stream>>>(bsum, nb, row_ptr, N, E);
  scan3_k<<<nb, 1024, 0, stream>>>(cnt, bsum, row_ptr, cursor, N);
  fill_k<<<(E+255)/256, 256, 0, stream>>>(esrc, edst, cursor, csr_src, E);

  // layer 1
  gemm128_k<<<512, 256, 0, stream>>>(x, W1, b1, bufA, N);
  gat_agg_k<<<(N+3)/4, 256, 0, stream>>>(bufA, att1, row_ptr, csr_src, bufB, N);
  // layer 2
  gemm128_k<<<512, 256, 0, stream>>>(bufB, W2, b2, bufA, N);
  gat_agg_k<<<(N+3)/4, 256, 0, stream>>>(bufA, att2, row_ptr, csr_src, bufB, N);
  // head
  mlp_k<<<512, 256, 0, stream>>>(bufB, Wp1, bp1, Wp2, bp2, out, N);
}

// Round 2
// 312.749 us; speedup vs baseline: 1.1869x; 1.1869x over previous
//
#include <hip/hip_runtime.h>
#include <math.h>

// ================= CSR build (unchanged, verified) =================

__global__ void count_k(const int* __restrict__ dst, int* __restrict__ cnt, int E){
  int e = blockIdx.x*blockDim.x + threadIdx.x;
  if(e < E) atomicAdd(&cnt[dst[e]], 1);
}

__global__ void scan1_k(const int* __restrict__ cnt, int* __restrict__ bsum, int n){
  __shared__ int ws[16];
  int i = blockIdx.x*1024 + threadIdx.x;
  int v = (i < n) ? cnt[i] : 0;
  #pragma unroll
  for(int m=1;m<64;m<<=1) v += __shfl_xor(v, m);
  if((threadIdx.x & 63) == 0) ws[threadIdx.x >> 6] = v;
  __syncthreads();
  if(threadIdx.x == 0){
    int s = 0;
    #pragma unroll
    for(int w=0; w<16; w++) s += ws[w];
    bsum[blockIdx.x] = s;
  }
}

__global__ void scan2_k(int* __restrict__ bsum, int nb, int* __restrict__ row_ptr, int n, int E){
  if(threadIdx.x==0 && blockIdx.x==0){
    int s=0;
    for(int b=0;b<nb;b++){ int v=bsum[b]; bsum[b]=s; s+=v; }
    row_ptr[n] = E;
  }
}

__global__ void scan3_k(const int* __restrict__ cnt, const int* __restrict__ bsum,
                        int* __restrict__ row_ptr, int* __restrict__ cursor, int n){
  __shared__ int sm[1024];
  int i = blockIdx.x*1024 + threadIdx.x;
  int v = (i<n)? cnt[i] : 0;
  sm[threadIdx.x] = v;
  __syncthreads();
  for(int off=1; off<1024; off<<=1){
    int t = (threadIdx.x>=off)? sm[threadIdx.x-off] : 0;
    __syncthreads();
    sm[threadIdx.x] += t;
    __syncthreads();
  }
  if(i<n){
    int ex = sm[threadIdx.x] - v + bsum[blockIdx.x];
    row_ptr[i] = ex;
    cursor[i] = ex;
  }
}

__global__ void fill_k(const int* __restrict__ src, const int* __restrict__ dst,
                       int* __restrict__ cursor, int* __restrict__ csr_src, int E){
  int e = blockIdx.x*blockDim.x + threadIdx.x;
  if(e < E){
    int p = atomicAdd(&cursor[dst[e]], 1);
    csr_src[p] = src[e];
  }
}

// ================= small prep kernels =================

// WT[k][j] = W[j][k], 128x128
__global__ __launch_bounds__(256) void transpose128_k(const float* __restrict__ W, float* __restrict__ WT){
  __shared__ float tile[32][33];
  int b = blockIdx.x;          // 16 blocks
  int tx = (b & 3) * 32;       // col tile in W
  int ty = (b >> 2) * 32;      // row tile in W
  int c = threadIdx.x & 31;
  int r0 = (threadIdx.x >> 5) * 4;
  #pragma unroll
  for(int i=0;i<4;i++)
    tile[r0+i][c] = W[(size_t)(ty + r0 + i)*128 + tx + c];
  __syncthreads();
  #pragma unroll
  for(int i=0;i<4;i++)
    WT[(size_t)(tx + r0 + i)*128 + ty + c] = tile[c][r0+i];
}

// Fold linear MLP: wfold[k] = sum_j Wp2[j]*Wp1[j][k];  wfold[128] = bp2 + sum_j Wp2[j]*bp1[j]
__global__ void fold_k(const float* __restrict__ Wp1, const float* __restrict__ bp1,
                       const float* __restrict__ Wp2, const float* __restrict__ bp2,
                       float* __restrict__ wfold){
  int k = blockIdx.x*blockDim.x + threadIdx.x;
  if(k < 128){
    float s = 0.f;
    for(int j=0;j<64;j++) s += Wp2[j]*Wp1[(size_t)j*128 + k];
    wfold[k] = s;
  } else if(k == 128){
    float s = bp2[0];
    for(int j=0;j<64;j++) s += Wp2[j]*bp1[j];
    wfold[128] = s;
  }
}

// ================= GEMM: Ybf16 = X @ W^T + b  (X:[n][128] f32, WT:[k][j] f32 pre-transposed) =================
// block = 128 threads (2 waves), 64 rows/block. XT staged transposed in LDS.
// lane tile 8 rows x 8 cols (outer product), wave tile 32 rows x 128 cols.

__device__ __forceinline__ unsigned pack_bf2(float lo, float hi){
  unsigned ul = __float_as_uint(lo); ul += 0x7fffu + ((ul>>16)&1u);
  unsigned uh = __float_as_uint(hi); uh += 0x7fffu + ((uh>>16)&1u);
  return (uh & 0xffff0000u) | (ul >> 16);
}

__global__ __launch_bounds__(128) void gemm_bf_k(const float* __restrict__ X,
    const float* __restrict__ WT, const float* __restrict__ b,
    unsigned short* __restrict__ Ybf, int nrows){
  __shared__ float XT[128*68];       // [k][r], pad 68
  int t = threadIdx.x;
  int r = t >> 1;
  int kh = (t & 1) * 64;
  int row = blockIdx.x*64 + r;
  const float* xrow = &X[(size_t)min(row, nrows-1)*128];
  bool rok = row < nrows;
  #pragma unroll
  for(int q=0;q<16;q++){
    float4 v = rok ? *(const float4*)&xrow[kh + 4*q] : make_float4(0.f,0.f,0.f,0.f);
    XT[(kh+4*q+0)*68 + r] = v.x;
    XT[(kh+4*q+1)*68 + r] = v.y;
    XT[(kh+4*q+2)*68 + r] = v.z;
    XT[(kh+4*q+3)*68 + r] = v.w;
  }
  __syncthreads();

  int wv = t >> 6, lane = t & 63;
  int rg = lane >> 4, cg = lane & 15;
  int rbase = wv*32 + rg*8;
  int cbase = cg*8;

  float acc[8][8];
  #pragma unroll
  for(int i=0;i<8;i++)
    #pragma unroll
    for(int j=0;j<8;j++) acc[i][j] = 0.f;

  #pragma unroll 4
  for(int k=0;k<128;k++){
    float4 x0 = *(const float4*)&XT[k*68 + rbase];
    float4 x1 = *(const float4*)&XT[k*68 + rbase + 4];
    float4 w0 = *(const float4*)&WT[(size_t)k*128 + cbase];
    float4 w1 = *(const float4*)&WT[(size_t)k*128 + cbase + 4];
    float xs[8] = {x0.x,x0.y,x0.z,x0.w,x1.x,x1.y,x1.z,x1.w};
    float wsv[8] = {w0.x,w0.y,w0.z,w0.w,w1.x,w1.y,w1.z,w1.w};
    #pragma unroll
    for(int i=0;i<8;i++)
      #pragma unroll
      for(int j=0;j<8;j++)
        acc[i][j] += xs[i]*wsv[j];
  }

  float4 bb0 = *(const float4*)&b[cbase];
  float4 bb1 = *(const float4*)&b[cbase+4];
  float bs[8] = {bb0.x,bb0.y,bb0.z,bb0.w,bb1.x,bb1.y,bb1.z,bb1.w};

  #pragma unroll
  for(int i=0;i<8;i++){
    int orow = blockIdx.x*64 + rbase + i;
    if(orow < nrows){
      float v0 = acc[i][0]+bs[0], v1 = acc[i][1]+bs[1], v2 = acc[i][2]+bs[2], v3 = acc[i][3]+bs[3];
      float v4 = acc[i][4]+bs[4], v5 = acc[i][5]+bs[5], v6 = acc[i][6]+bs[6], v7 = acc[i][7]+bs[7];
      uint4 o;
      o.x = pack_bf2(v0,v1); o.y = pack_bf2(v2,v3); o.z = pack_bf2(v4,v5); o.w = pack_bf2(v6,v7);
      *(uint4*)&Ybf[(size_t)orow*128 + cbase] = o;
    }
  }
}

// ================= GATv2 fused edge phase (bf16 gathers, 2 edges/iter) =================
// wave per node; lane l: half = l>>5 (edge slot), channels c4 = (l&31)*4.
// lanes 0-15 of each half = head 0 channels, 16-31 = head 1. Online softmax per lane,
// halves merged at the end. FUSE=1: fused folded-MLP + sigmoid epilogue.

template<int FUSE>
__global__ __launch_bounds__(256) void gat_v2_k(
    const unsigned short* __restrict__ XWbf,   // [n][128] bf16
    const float* __restrict__ att,             // [128]
    const int* __restrict__ row_ptr, const int* __restrict__ csr_src,
    float* __restrict__ outp,                  // FUSE=0: [n][128] f32; FUSE=1: [n]
    const float* __restrict__ wfold,           // [129], FUSE=1 only
    int n)
{
  int wid = threadIdx.x >> 6, lane = threadIdx.x & 63;
  int node = blockIdx.x*4 + wid;
  if(node >= n) return;
  int half = lane >> 5;
  int c4 = (lane & 31) * 4;

  float4 a4 = *(const float4*)&att[c4];
  uint2 dxu = *(const uint2*)&XWbf[(size_t)node*128 + c4];
  float xd0 = __uint_as_float(dxu.x << 16);
  float xd1 = __uint_as_float(dxu.x & 0xffff0000u);
  float xd2 = __uint_as_float(dxu.y << 16);
  float xd3 = __uint_as_float(dxu.y & 0xffff0000u);

  int beg = row_ptr[node], end = row_ptr[node+1];
  float m = -1e30f, s = 0.f;
  float ac0=0.f, ac1=0.f, ac2=0.f, ac3=0.f;

  for(int i = beg; i < end; i += 2){
    int e = i + half;
    bool ok = e < end;
    int srcn = ok ? csr_src[e] : node;
    uint2 g = *(const uint2*)&XWbf[(size_t)srcn*128 + c4];
    float x0 = __uint_as_float(g.x << 16);
    float x1 = __uint_as_float(g.x & 0xffff0000u);
    float x2 = __uint_as_float(g.y << 16);
    float x3 = __uint_as_float(g.y & 0xffff0000u);
    float v0 = xd0+x0, v1 = xd1+x1, v2 = xd2+x2, v3 = xd3+x3;
    v0 = fmaxf(v0,0.f) + 0.2f*fminf(v0,0.f);
    v1 = fmaxf(v1,0.f) + 0.2f*fminf(v1,0.f);
    v2 = fmaxf(v2,0.f) + 0.2f*fminf(v2,0.f);
    v3 = fmaxf(v3,0.f) + 0.2f*fminf(v3,0.f);
    float p = v0*a4.x + v1*a4.y + v2*a4.z + v3*a4.w;
    p += __shfl_xor(p, 1);
    p += __shfl_xor(p, 2);
    p += __shfl_xor(p, 4);
    p += __shfl_xor(p, 8);
    if(!ok) p = -2e30f;
    float mn = fmaxf(m, p);
    float ex = __expf(p - mn);
    float sc = __expf(m - mn);
    s = s*sc + ex;
    ac0 = ac0*sc + ex*x0;
    ac1 = ac1*sc + ex*x1;
    ac2 = ac2*sc + ex*x2;
    ac3 = ac3*sc + ex*x3;
    m = mn;
  }

  // merge the two lane-halves' online-softmax states
  float mo = __shfl_xor(m, 32), so = __shfl_xor(s, 32);
  float bo0 = __shfl_xor(ac0,32), bo1 = __shfl_xor(ac1,32);
  float bo2 = __shfl_xor(ac2,32), bo3 = __shfl_xor(ac3,32);
  float M  = fmaxf(m, mo);
  float w1 = __expf(m - M), w2 = __expf(mo - M);
  float S  = s*w1 + so*w2;
  float o0 = ac0*w1 + bo0*w2;
  float o1 = ac1*w1 + bo1*w2;
  float o2 = ac2*w1 + bo2*w2;
  float o3 = ac3*w1 + bo3*w2;
  float inv = (S > 0.f) ? 1.f/S : 0.f;
  o0 = fmaxf(o0*inv, 0.f);   // relu fused
  o1 = fmaxf(o1*inv, 0.f);
  o2 = fmaxf(o2*inv, 0.f);
  o3 = fmaxf(o3*inv, 0.f);

  if(FUSE == 0){
    if(half == 0)
      *(float4*)&outp[(size_t)node*128 + c4] = make_float4(o0,o1,o2,o3);
  } else {
    float4 wf = *(const float4*)&wfold[c4];
    float tt = o0*wf.x + o1*wf.y + o2*wf.z + o3*wf.w;
    tt += __shfl_xor(tt, 1);
    tt += __shfl_xor(tt, 2);
    tt += __shfl_xor(tt, 4);
    tt += __shfl_xor(tt, 8);
    tt += __shfl_xor(tt, 16);
    if(lane == 0)
      outp[node] = 1.f/(1.f + __expf(-(tt + wfold[128])));
  }
}

// ================= launcher =================

static inline size_t alignup(size_t v){ return (v + 255) & ~(size_t)255; }

extern "C" void kernel_launch(void* const* d_in, const int* in_sizes, int n_in,
                              void* d_out, int out_size, void* d_ws, size_t ws_size,
                              hipStream_t stream) {
  const float* x    = (const float*)d_in[0];
  const int*   ei   = (const int*)  d_in[1];
  const float* W1   = (const float*)d_in[2];
  const float* b1   = (const float*)d_in[3];
  const float* att1 = (const float*)d_in[4];
  const float* W2   = (const float*)d_in[5];
  const float* b2   = (const float*)d_in[6];
  const float* att2 = (const float*)d_in[7];
  const float* Wp1  = (const float*)d_in[8];
  const float* bp1  = (const float*)d_in[9];
  const float* Wp2  = (const float*)d_in[10];
  const float* bp2  = (const float*)d_in[11];
  float* out = (float*)d_out;

  int N = in_sizes[0] / 128;
  int E = in_sizes[1] / 2;

  char* ws = (char*)d_ws;
  size_t off = 0;
  float* G1            = (float*)(ws + off); off = alignup(off + (size_t)N*128*sizeof(float));
  unsigned short* XWbf = (unsigned short*)(ws + off); off = alignup(off + (size_t)N*128*sizeof(unsigned short));
  int* csr_src  = (int*)(ws + off); off = alignup(off + (size_t)E*sizeof(int));
  int* row_ptr  = (int*)(ws + off); off = alignup(off + (size_t)(N+1)*sizeof(int));
  int* cursor   = (int*)(ws + off); off = alignup(off + (size_t)N*sizeof(int));
  int* cnt      = (int*)(ws + off); off = alignup(off + (size_t)N*sizeof(int));
  int* bsum     = (int*)(ws + off); off = alignup(off + 64*sizeof(int));
  float* WT1    = (float*)(ws + off); off = alignup(off + 128*128*sizeof(float));
  float* WT2    = (float*)(ws + off); off = alignup(off + 128*128*sizeof(float));
  float* wfold  = (float*)(ws + off); off = alignup(off + 129*sizeof(float));

  const int* esrc = ei;
  const int* edst = ei + E;

  hipMemsetAsync(cnt, 0, (size_t)N*sizeof(int), stream);

  int nb = (N + 1023) / 1024;
  count_k<<<(E+255)/256, 256, 0, stream>>>(edst, cnt, E);
  scan1_k<<<nb, 1024, 0, stream>>>(cnt, bsum, N);
  scan2_k<<<1, 64, 0, stream>>>(bsum, nb, row_ptr, N, E);
  scan3_k<<<nb, 1024, 0, stream>>>(cnt, bsum, row_ptr, cursor, N);
  fill_k<<<(E+255)/256, 256, 0, stream>>>(esrc, edst, cursor, csr_src, E);

  transpose128_k<<<16, 256, 0, stream>>>(W1, WT1);
  transpose128_k<<<16, 256, 0, stream>>>(W2, WT2);
  fold_k<<<1, 192, 0, stream>>>(Wp1, bp1, Wp2, bp2, wfold);

  int gb = (N + 63) / 64;
  // layer 1
  gemm_bf_k<<<gb, 128, 0, stream>>>(x, WT1, b1, XWbf, N);
  gat_v2_k<0><<<(N+3)/4, 256, 0, stream>>>(XWbf, att1, row_ptr, csr_src, G1, nullptr, N);
  // layer 2
  gemm_bf_k<<<gb, 128, 0, stream>>>(G1, WT2, b2, XWbf, N);
  gat_v2_k<1><<<(N+3)/4, 256, 0, stream>>>(XWbf, att2, row_ptr, csr_src, out, wfold, N);
}

// Round 3
// 260.154 us; speedup vs baseline: 1.4268x; 1.2022x over previous
//
#include <hip/hip_runtime.h>
#include <math.h>

// ================= CSR build =================

__global__ void count_k(const int* __restrict__ dst, int* __restrict__ cnt, int E){
  int e = blockIdx.x*blockDim.x + threadIdx.x;
  if(e < E) atomicAdd(&cnt[dst[e]], 1);
}

__global__ void scan1_k(const int* __restrict__ cnt, int* __restrict__ bsum, int n){
  __shared__ int ws[16];
  int i = blockIdx.x*1024 + threadIdx.x;
  int v = (i < n) ? cnt[i] : 0;
  #pragma unroll
  for(int m=1;m<64;m<<=1) v += __shfl_xor(v, m);
  if((threadIdx.x & 63) == 0) ws[threadIdx.x >> 6] = v;
  __syncthreads();
  if(threadIdx.x == 0){
    int s = 0;
    #pragma unroll
    for(int w=0; w<16; w++) s += ws[w];
    bsum[blockIdx.x] = s;
  }
}

// parallel exclusive scan of nb (<=64) block sums with one wave
__global__ void scan2_k(int* __restrict__ bsum, int nb, int* __restrict__ row_ptr, int n, int E){
  int lane = threadIdx.x & 63;
  int v = (lane < nb) ? bsum[lane] : 0;
  int inc = v;
  #pragma unroll
  for(int off=1; off<64; off<<=1){
    int t = __shfl_up(inc, off);
    if(lane >= off) inc += t;
  }
  if(lane < nb) bsum[lane] = inc - v;
  if(lane == 0) row_ptr[n] = E;
}

__global__ void scan3_k(const int* __restrict__ cnt, const int* __restrict__ bsum,
                        int* __restrict__ row_ptr, int* __restrict__ cursor, int n){
  __shared__ int sm[1024];
  int i = blockIdx.x*1024 + threadIdx.x;
  int v = (i<n)? cnt[i] : 0;
  sm[threadIdx.x] = v;
  __syncthreads();
  for(int off=1; off<1024; off<<=1){
    int t = (threadIdx.x>=off)? sm[threadIdx.x-off] : 0;
    __syncthreads();
    sm[threadIdx.x] += t;
    __syncthreads();
  }
  if(i<n){
    int ex = sm[threadIdx.x] - v + bsum[blockIdx.x];
    row_ptr[i] = ex;
    cursor[i] = ex;
  }
}

__global__ void fill_k(const int* __restrict__ src, const int* __restrict__ dst,
                       int* __restrict__ cursor, int* __restrict__ csr_src, int E){
  int e = blockIdx.x*blockDim.x + threadIdx.x;
  if(e < E){
    int p = atomicAdd(&cursor[dst[e]], 1);
    csr_src[p] = src[e];
  }
}

// ================= prep =================

__global__ __launch_bounds__(256) void transpose128_k(const float* __restrict__ W, float* __restrict__ WT){
  __shared__ float tile[32][33];
  int b = blockIdx.x;
  int tx = (b & 3) * 32;
  int ty = (b >> 2) * 32;
  int c = threadIdx.x & 31;
  int r0 = (threadIdx.x >> 5) * 4;
  #pragma unroll
  for(int i=0;i<4;i++)
    tile[r0+i][c] = W[(size_t)(ty + r0 + i)*128 + tx + c];
  __syncthreads();
  #pragma unroll
  for(int i=0;i<4;i++)
    WT[(size_t)(tx + r0 + i)*128 + ty + c] = tile[c][r0+i];
}

__global__ void fold_k(const float* __restrict__ Wp1, const float* __restrict__ bp1,
                       const float* __restrict__ Wp2, const float* __restrict__ bp2,
                       float* __restrict__ wfold){
  int k = blockIdx.x*blockDim.x + threadIdx.x;
  if(k < 128){
    float s = 0.f;
    for(int j=0;j<64;j++) s += Wp2[j]*Wp1[(size_t)j*128 + k];
    wfold[k] = s;
  } else if(k == 128){
    float s = bp2[0];
    for(int j=0;j<64;j++) s += Wp2[j]*bp1[j];
    wfold[128] = s;
  }
}

// ================= GEMM (f32 in, bf16 out) =================

__device__ __forceinline__ unsigned pack_bf2(float lo, float hi){
  unsigned ul = __float_as_uint(lo); ul += 0x7fffu + ((ul>>16)&1u);
  unsigned uh = __float_as_uint(hi); uh += 0x7fffu + ((uh>>16)&1u);
  return (uh & 0xffff0000u) | (ul >> 16);
}

__global__ __launch_bounds__(128) void gemm_bf_k(const float* __restrict__ X,
    const float* __restrict__ WT, const float* __restrict__ b,
    unsigned short* __restrict__ Ybf, int nrows){
  __shared__ float XT[128*68];
  int t = threadIdx.x;
  int r = t >> 1;
  int kh = (t & 1) * 64;
  int row = blockIdx.x*64 + r;
  const float* xrow = &X[(size_t)min(row, nrows-1)*128];
  bool rok = row < nrows;
  #pragma unroll
  for(int q=0;q<16;q++){
    float4 v = rok ? *(const float4*)&xrow[kh + 4*q] : make_float4(0.f,0.f,0.f,0.f);
    XT[(kh+4*q+0)*68 + r] = v.x;
    XT[(kh+4*q+1)*68 + r] = v.y;
    XT[(kh+4*q+2)*68 + r] = v.z;
    XT[(kh+4*q+3)*68 + r] = v.w;
  }
  __syncthreads();

  int wv = t >> 6, lane = t & 63;
  int rg = lane >> 4, cg = lane & 15;
  int rbase = wv*32 + rg*8;
  int cbase = cg*8;

  float acc[8][8];
  #pragma unroll
  for(int i=0;i<8;i++)
    #pragma unroll
    for(int j=0;j<8;j++) acc[i][j] = 0.f;

  #pragma unroll 4
  for(int k=0;k<128;k++){
    float4 x0 = *(const float4*)&XT[k*68 + rbase];
    float4 x1 = *(const float4*)&XT[k*68 + rbase + 4];
    float4 w0 = *(const float4*)&WT[(size_t)k*128 + cbase];
    float4 w1 = *(const float4*)&WT[(size_t)k*128 + cbase + 4];
    float xs[8] = {x0.x,x0.y,x0.z,x0.w,x1.x,x1.y,x1.z,x1.w};
    float wsv[8] = {w0.x,w0.y,w0.z,w0.w,w1.x,w1.y,w1.z,w1.w};
    #pragma unroll
    for(int i=0;i<8;i++)
      #pragma unroll
      for(int j=0;j<8;j++)
        acc[i][j] += xs[i]*wsv[j];
  }

  float4 bb0 = *(const float4*)&b[cbase];
  float4 bb1 = *(const float4*)&b[cbase+4];
  float bs[8] = {bb0.x,bb0.y,bb0.z,bb0.w,bb1.x,bb1.y,bb1.z,bb1.w};

  #pragma unroll
  for(int i=0;i<8;i++){
    int orow = blockIdx.x*64 + rbase + i;
    if(orow < nrows){
      uint4 o;
      o.x = pack_bf2(acc[i][0]+bs[0], acc[i][1]+bs[1]);
      o.y = pack_bf2(acc[i][2]+bs[2], acc[i][3]+bs[3]);
      o.z = pack_bf2(acc[i][4]+bs[4], acc[i][5]+bs[5]);
      o.w = pack_bf2(acc[i][6]+bs[6], acc[i][7]+bs[7]);
      *(uint4*)&Ybf[(size_t)orow*128 + cbase] = o;
    }
  }
}

// ================= GATv2 edge phase v3 =================
// wave per node; 16 lanes per edge (4 edge slots g=lane>>4), lane owns 8 channels
// (c8 = (lane&15)*8; j<8 -> head0, j>=8 -> head1). No max-tracking (logits ~N(0,1.4),
// clamped at 60): plain exp-sum, fma accumulate. DPP reduces on the VALU pipe.

#define BFLO(u) __uint_as_float((u)<<16)
#define BFHI(u) __uint_as_float((u)&0xffff0000u)
#define DPP_ADD(v, ctrl) { int _t = __builtin_amdgcn_update_dpp(0, __float_as_int(v), ctrl, 0xF, 0xF, true); (v) += __int_as_float(_t); }

template<int FUSE>
__global__ __launch_bounds__(256) void gat_v3_k(
    const unsigned short* __restrict__ XWbf,
    const float* __restrict__ att,
    const int* __restrict__ row_ptr, const int* __restrict__ csr_src,
    float* __restrict__ outp, const float* __restrict__ wfold, int n)
{
  int wid = threadIdx.x >> 6, lane = threadIdx.x & 63;
  int node = blockIdx.x*4 + wid;
  if(node >= n) return;
  int g = lane >> 4;
  int c8 = (lane & 15) * 8;

  float4 a0 = *(const float4*)&att[c8];
  float4 a1 = *(const float4*)&att[c8+4];
  uint4 du = *(const uint4*)&XWbf[(size_t)node*128 + c8];
  float xd0=BFLO(du.x), xd1=BFHI(du.x), xd2=BFLO(du.y), xd3=BFHI(du.y);
  float xd4=BFLO(du.z), xd5=BFHI(du.z), xd6=BFLO(du.w), xd7=BFHI(du.w);

  int beg = row_ptr[node], end = row_ptr[node+1];
  float s = 0.f;
  float ac0=0.f, ac1=0.f, ac2=0.f, ac3=0.f, ac4=0.f, ac5=0.f, ac6=0.f, ac7=0.f;

  for(int i = beg; i < end; i += 8){
    int e0 = i + g, e1 = i + 4 + g;
    int i0 = min(e0, end-1), i1 = min(e1, end-1);
    int s0 = csr_src[i0];
    int s1 = csr_src[i1];
    uint4 u0 = *(const uint4*)&XWbf[(size_t)s0*128 + c8];
    uint4 u1 = *(const uint4*)&XWbf[(size_t)s1*128 + c8];

    // --- edge slot e0 ---
    {
      float x0=BFLO(u0.x), x1=BFHI(u0.x), x2=BFLO(u0.y), x3=BFHI(u0.y);
      float x4=BFLO(u0.z), x5=BFHI(u0.z), x6=BFLO(u0.w), x7=BFHI(u0.w);
      float v0=xd0+x0, v1=xd1+x1, v2=xd2+x2, v3=xd3+x3;
      float v4=xd4+x4, v5=xd5+x5, v6=xd6+x6, v7=xd7+x7;
      v0 = fmaxf(v0,0.f)+0.2f*fminf(v0,0.f); v1 = fmaxf(v1,0.f)+0.2f*fminf(v1,0.f);
      v2 = fmaxf(v2,0.f)+0.2f*fminf(v2,0.f); v3 = fmaxf(v3,0.f)+0.2f*fminf(v3,0.f);
      v4 = fmaxf(v4,0.f)+0.2f*fminf(v4,0.f); v5 = fmaxf(v5,0.f)+0.2f*fminf(v5,0.f);
      v6 = fmaxf(v6,0.f)+0.2f*fminf(v6,0.f); v7 = fmaxf(v7,0.f)+0.2f*fminf(v7,0.f);
      float p = v0*a0.x + v1*a0.y + v2*a0.z + v3*a0.w
              + v4*a1.x + v5*a1.y + v6*a1.z + v7*a1.w;
      DPP_ADD(p, 0xB1);   // xor1
      DPP_ADD(p, 0x4E);   // xor2
      DPP_ADD(p, 0x141);  // xor4 (row_half_mirror; quads equal after first two)
      float ex = (e0 < end) ? __expf(fminf(p, 60.f)) : 0.f;
      s += ex;
      ac0 += ex*x0; ac1 += ex*x1; ac2 += ex*x2; ac3 += ex*x3;
      ac4 += ex*x4; ac5 += ex*x5; ac6 += ex*x6; ac7 += ex*x7;
    }
    // --- edge slot e1 ---
    {
      float x0=BFLO(u1.x), x1=BFHI(u1.x), x2=BFLO(u1.y), x3=BFHI(u1.y);
      float x4=BFLO(u1.z), x5=BFHI(u1.z), x6=BFLO(u1.w), x7=BFHI(u1.w);
      float v0=xd0+x0, v1=xd1+x1, v2=xd2+x2, v3=xd3+x3;
      float v4=xd4+x4, v5=xd5+x5, v6=xd6+x6, v7=xd7+x7;
      v0 = fmaxf(v0,0.f)+0.2f*fminf(v0,0.f); v1 = fmaxf(v1,0.f)+0.2f*fminf(v1,0.f);
      v2 = fmaxf(v2,0.f)+0.2f*fminf(v2,0.f); v3 = fmaxf(v3,0.f)+0.2f*fminf(v3,0.f);
      v4 = fmaxf(v4,0.f)+0.2f*fminf(v4,0.f); v5 = fmaxf(v5,0.f)+0.2f*fminf(v5,0.f);
      v6 = fmaxf(v6,0.f)+0.2f*fminf(v6,0.f); v7 = fmaxf(v7,0.f)+0.2f*fminf(v7,0.f);
      float p = v0*a0.x + v1*a0.y + v2*a0.z + v3*a0.w
              + v4*a1.x + v5*a1.y + v6*a1.z + v7*a1.w;
      DPP_ADD(p, 0xB1);
      DPP_ADD(p, 0x4E);
      DPP_ADD(p, 0x141);
      float ex = (e1 < end) ? __expf(fminf(p, 60.f)) : 0.f;
      s += ex;
      ac0 += ex*x0; ac1 += ex*x1; ac2 += ex*x2; ac3 += ex*x3;
      ac4 += ex*x4; ac5 += ex*x5; ac6 += ex*x6; ac7 += ex*x7;
    }
  }

  // merge 4 edge-slot groups (lanes differing in bits 4,5)
  s   += __shfl_xor(s,16);   s   += __shfl_xor(s,32);
  ac0 += __shfl_xor(ac0,16); ac0 += __shfl_xor(ac0,32);
  ac1 += __shfl_xor(ac1,16); ac1 += __shfl_xor(ac1,32);
  ac2 += __shfl_xor(ac2,16); ac2 += __shfl_xor(ac2,32);
  ac3 += __shfl_xor(ac3,16); ac3 += __shfl_xor(ac3,32);
  ac4 += __shfl_xor(ac4,16); ac4 += __shfl_xor(ac4,32);
  ac5 += __shfl_xor(ac5,16); ac5 += __shfl_xor(ac5,32);
  ac6 += __shfl_xor(ac6,16); ac6 += __shfl_xor(ac6,32);
  ac7 += __shfl_xor(ac7,16); ac7 += __shfl_xor(ac7,32);

  float inv = (s > 0.f) ? 1.f/s : 0.f;
  float o0 = fmaxf(ac0*inv,0.f), o1 = fmaxf(ac1*inv,0.f);
  float o2 = fmaxf(ac2*inv,0.f), o3 = fmaxf(ac3*inv,0.f);
  float o4 = fmaxf(ac4*inv,0.f), o5 = fmaxf(ac5*inv,0.f);
  float o6 = fmaxf(ac6*inv,0.f), o7 = fmaxf(ac7*inv,0.f);

  if(FUSE == 0){
    if(lane < 16){
      *(float4*)&outp[(size_t)node*128 + c8]     = make_float4(o0,o1,o2,o3);
      *(float4*)&outp[(size_t)node*128 + c8 + 4] = make_float4(o4,o5,o6,o7);
    }
  } else {
    float4 wf0 = *(const float4*)&wfold[c8];
    float4 wf1 = *(const float4*)&wfold[c8+4];
    float tt = o0*wf0.x + o1*wf0.y + o2*wf0.z + o3*wf0.w
             + o4*wf1.x + o5*wf1.y + o6*wf1.z + o7*wf1.w;
    DPP_ADD(tt, 0xB1);
    DPP_ADD(tt, 0x4E);
    DPP_ADD(tt, 0x141);
    DPP_ADD(tt, 0x140);  // xor8 (row_mirror; 8-groups equal after first three)
    if(lane == 0)
      outp[node] = 1.f/(1.f + __expf(-(tt + wfold[128])));
  }
}

// ================= launcher =================

static inline size_t alignup(size_t v){ return (v + 255) & ~(size_t)255; }

extern "C" void kernel_launch(void* const* d_in, const int* in_sizes, int n_in,
                              void* d_out, int out_size, void* d_ws, size_t ws_size,
                              hipStream_t stream) {
  const float* x    = (const float*)d_in[0];
  const int*   ei   = (const int*)  d_in[1];
  const float* W1   = (const float*)d_in[2];
  const float* b1   = (const float*)d_in[3];
  const float* att1 = (const float*)d_in[4];
  const float* W2   = (const float*)d_in[5];
  const float* b2   = (const float*)d_in[6];
  const float* att2 = (const float*)d_in[7];
  const float* Wp1  = (const float*)d_in[8];
  const float* bp1  = (const float*)d_in[9];
  const float* Wp2  = (const float*)d_in[10];
  const float* bp2  = (const float*)d_in[11];
  float* out = (float*)d_out;

  int N = in_sizes[0] / 128;
  int E = in_sizes[1] / 2;

  char* ws = (char*)d_ws;
  size_t off = 0;
  float* G1            = (float*)(ws + off); off = alignup(off + (size_t)N*128*sizeof(float));
  unsigned short* XWbf = (unsigned short*)(ws + off); off = alignup(off + (size_t)N*128*sizeof(unsigned short));
  int* csr_src  = (int*)(ws + off); off = alignup(off + (size_t)E*sizeof(int));
  int* row_ptr  = (int*)(ws + off); off = alignup(off + (size_t)(N+1)*sizeof(int));
  int* cursor   = (int*)(ws + off); off = alignup(off + (size_t)N*sizeof(int));
  int* cnt      = (int*)(ws + off); off = alignup(off + (size_t)N*sizeof(int));
  int* bsum     = (int*)(ws + off); off = alignup(off + 64*sizeof(int));
  float* WT1    = (float*)(ws + off); off = alignup(off + 128*128*sizeof(float));
  float* WT2    = (float*)(ws + off); off = alignup(off + 128*128*sizeof(float));
  float* wfold  = (float*)(ws + off); off = alignup(off + 129*sizeof(float));

  const int* esrc = ei;
  const int* edst = ei + E;

  hipMemsetAsync(cnt, 0, (size_t)N*sizeof(int), stream);

  int nb = (N + 1023) / 1024;
  count_k<<<(E+255)/256, 256, 0, stream>>>(edst, cnt, E);
  scan1_k<<<nb, 1024, 0, stream>>>(cnt, bsum, N);
  scan2_k<<<1, 64, 0, stream>>>(bsum, nb, row_ptr, N, E);
  scan3_k<<<nb, 1024, 0, stream>>>(cnt, bsum, row_ptr, cursor, N);
  fill_k<<<(E+255)/256, 256, 0, stream>>>(esrc, edst, cursor, csr_src, E);

  transpose128_k<<<16, 256, 0, stream>>>(W1, WT1);
  transpose128_k<<<16, 256, 0, stream>>>(W2, WT2);
  fold_k<<<1, 192, 0, stream>>>(Wp1, bp1, Wp2, bp2, wfold);

  int gb = (N + 63) / 64;
  // layer 1
  gemm_bf_k<<<gb, 128, 0, stream>>>(x, WT1, b1, XWbf, N);
  gat_v3_k<0><<<(N+3)/4, 256, 0, stream>>>(XWbf, att1, row_ptr, csr_src, G1, nullptr, N);
  // layer 2
  gemm_bf_k<<<gb, 128, 0, stream>>>(G1, WT2, b2, XWbf, N);
  gat_v3_k<1><<<(N+3)/4, 256, 0, stream>>>(XWbf, att2, row_ptr, csr_src, out, wfold, N);
}

// Round 4
// 227.336 us; speedup vs baseline: 1.6328x; 1.1444x over previous
//
#include <hip/hip_runtime.h>
#include <math.h>

// ================= CSR build =================
// v4: slot pre-assignment (atomic in count phase, return stored coalesced),
// then atomic-free scatter -> no dependent atomic round-trip in fill.

__global__ void countslot_k(const int* __restrict__ dst, int* __restrict__ cnt,
                            int* __restrict__ slot, int E){
  int e = blockIdx.x*blockDim.x + threadIdx.x;
  if(e < E) slot[e] = atomicAdd(&cnt[dst[e]], 1);
}

__global__ void scan1_k(const int* __restrict__ cnt, int* __restrict__ bsum, int n){
  __shared__ int ws[16];
  int i = blockIdx.x*1024 + threadIdx.x;
  int v = (i < n) ? cnt[i] : 0;
  #pragma unroll
  for(int m=1;m<64;m<<=1) v += __shfl_xor(v, m);
  if((threadIdx.x & 63) == 0) ws[threadIdx.x >> 6] = v;
  __syncthreads();
  if(threadIdx.x == 0){
    int s = 0;
    #pragma unroll
    for(int w=0; w<16; w++) s += ws[w];
    bsum[blockIdx.x] = s;
  }
}

// parallel exclusive scan of nb (<=64) block sums with one wave
__global__ void scan2_k(int* __restrict__ bsum, int nb, int* __restrict__ row_ptr, int n, int E){
  int lane = threadIdx.x & 63;
  int v = (lane < nb) ? bsum[lane] : 0;
  int inc = v;
  #pragma unroll
  for(int off=1; off<64; off<<=1){
    int t = __shfl_up(inc, off);
    if(lane >= off) inc += t;
  }
  if(lane < nb) bsum[lane] = inc - v;
  if(lane == 0) row_ptr[n] = E;
}

__global__ void scan3_k(const int* __restrict__ cnt, const int* __restrict__ bsum,
                        int* __restrict__ row_ptr, int n){
  __shared__ int sm[1024];
  int i = blockIdx.x*1024 + threadIdx.x;
  int v = (i<n)? cnt[i] : 0;
  sm[threadIdx.x] = v;
  __syncthreads();
  for(int off=1; off<1024; off<<=1){
    int t = (threadIdx.x>=off)? sm[threadIdx.x-off] : 0;
    __syncthreads();
    sm[threadIdx.x] += t;
    __syncthreads();
  }
  if(i<n)
    row_ptr[i] = sm[threadIdx.x] - v + bsum[blockIdx.x];
}

__global__ void fill2_k(const int* __restrict__ src, const int* __restrict__ dst,
                        const int* __restrict__ slot, const int* __restrict__ row_ptr,
                        int* __restrict__ csr_src, int E){
  int e = blockIdx.x*blockDim.x + threadIdx.x;
  if(e < E)
    csr_src[row_ptr[dst[e]] + slot[e]] = src[e];
}

// ================= prep =================

__global__ __launch_bounds__(256) void transpose128_k(const float* __restrict__ W, float* __restrict__ WT){
  __shared__ float tile[32][33];
  int b = blockIdx.x;
  int tx = (b & 3) * 32;
  int ty = (b >> 2) * 32;
  int c = threadIdx.x & 31;
  int r0 = (threadIdx.x >> 5) * 4;
  #pragma unroll
  for(int i=0;i<4;i++)
    tile[r0+i][c] = W[(size_t)(ty + r0 + i)*128 + tx + c];
  __syncthreads();
  #pragma unroll
  for(int i=0;i<4;i++)
    WT[(size_t)(tx + r0 + i)*128 + ty + c] = tile[c][r0+i];
}

__global__ void fold_k(const float* __restrict__ Wp1, const float* __restrict__ bp1,
                       const float* __restrict__ Wp2, const float* __restrict__ bp2,
                       float* __restrict__ wfold){
  int k = blockIdx.x*blockDim.x + threadIdx.x;
  if(k < 128){
    float s = 0.f;
    for(int j=0;j<64;j++) s += Wp2[j]*Wp1[(size_t)j*128 + k];
    wfold[k] = s;
  } else if(k == 128){
    float s = bp2[0];
    for(int j=0;j<64;j++) s += Wp2[j]*bp1[j];
    wfold[128] = s;
  }
}

// ================= GEMM (f32 in, bf16 out) =================

__device__ __forceinline__ unsigned pack_bf2(float lo, float hi){
  unsigned ul = __float_as_uint(lo); ul += 0x7fffu + ((ul>>16)&1u);
  unsigned uh = __float_as_uint(hi); uh += 0x7fffu + ((uh>>16)&1u);
  return (uh & 0xffff0000u) | (ul >> 16);
}

__global__ __launch_bounds__(128) void gemm_bf_k(const float* __restrict__ X,
    const float* __restrict__ WT, const float* __restrict__ b,
    unsigned short* __restrict__ Ybf, int nrows){
  __shared__ float XT[128*68];
  int t = threadIdx.x;
  int r = t >> 1;
  int kh = (t & 1) * 64;
  int row = blockIdx.x*64 + r;
  const float* xrow = &X[(size_t)min(row, nrows-1)*128];
  bool rok = row < nrows;
  #pragma unroll
  for(int q=0;q<16;q++){
    float4 v = rok ? *(const float4*)&xrow[kh + 4*q] : make_float4(0.f,0.f,0.f,0.f);
    XT[(kh+4*q+0)*68 + r] = v.x;
    XT[(kh+4*q+1)*68 + r] = v.y;
    XT[(kh+4*q+2)*68 + r] = v.z;
    XT[(kh+4*q+3)*68 + r] = v.w;
  }
  __syncthreads();

  int wv = t >> 6, lane = t & 63;
  int rg = lane >> 4, cg = lane & 15;
  int rbase = wv*32 + rg*8;
  int cbase = cg*8;

  float acc[8][8];
  #pragma unroll
  for(int i=0;i<8;i++)
    #pragma unroll
    for(int j=0;j<8;j++) acc[i][j] = 0.f;

  #pragma unroll 4
  for(int k=0;k<128;k++){
    float4 x0 = *(const float4*)&XT[k*68 + rbase];
    float4 x1 = *(const float4*)&XT[k*68 + rbase + 4];
    float4 w0 = *(const float4*)&WT[(size_t)k*128 + cbase];
    float4 w1 = *(const float4*)&WT[(size_t)k*128 + cbase + 4];
    float xs[8] = {x0.x,x0.y,x0.z,x0.w,x1.x,x1.y,x1.z,x1.w};
    float wsv[8] = {w0.x,w0.y,w0.z,w0.w,w1.x,w1.y,w1.z,w1.w};
    #pragma unroll
    for(int i=0;i<8;i++)
      #pragma unroll
      for(int j=0;j<8;j++)
        acc[i][j] += xs[i]*wsv[j];
  }

  float4 bb0 = *(const float4*)&b[cbase];
  float4 bb1 = *(const float4*)&b[cbase+4];
  float bs[8] = {bb0.x,bb0.y,bb0.z,bb0.w,bb1.x,bb1.y,bb1.z,bb1.w};

  #pragma unroll
  for(int i=0;i<8;i++){
    int orow = blockIdx.x*64 + rbase + i;
    if(orow < nrows){
      uint4 o;
      o.x = pack_bf2(acc[i][0]+bs[0], acc[i][1]+bs[1]);
      o.y = pack_bf2(acc[i][2]+bs[2], acc[i][3]+bs[3]);
      o.z = pack_bf2(acc[i][4]+bs[4], acc[i][5]+bs[5]);
      o.w = pack_bf2(acc[i][6]+bs[6], acc[i][7]+bs[7]);
      *(uint4*)&Ybf[(size_t)orow*128 + cbase] = o;
    }
  }
}

// ================= GATv2 edge phase v3 =================
// wave per node; 16 lanes per edge (4 edge slots g=lane>>4), lane owns 8 channels
// (c8 = (lane&15)*8; j<8 -> head0, j>=8 -> head1). No max-tracking (logits ~N(0,1.4),
// clamped at 60): plain exp-sum, fma accumulate. DPP reduces on the VALU pipe.

#define BFLO(u) __uint_as_float((u)<<16)
#define BFHI(u) __uint_as_float((u)&0xffff0000u)
#define DPP_ADD(v, ctrl) { int _t = __builtin_amdgcn_update_dpp(0, __float_as_int(v), ctrl, 0xF, 0xF, true); (v) += __int_as_float(_t); }

template<int FUSE>
__global__ __launch_bounds__(256) void gat_v3_k(
    const unsigned short* __restrict__ XWbf,
    const float* __restrict__ att,
    const int* __restrict__ row_ptr, const int* __restrict__ csr_src,
    float* __restrict__ outp, const float* __restrict__ wfold, int n)
{
  int wid = threadIdx.x >> 6, lane = threadIdx.x & 63;
  int node = blockIdx.x*4 + wid;
  if(node >= n) return;
  int g = lane >> 4;
  int c8 = (lane & 15) * 8;

  float4 a0 = *(const float4*)&att[c8];
  float4 a1 = *(const float4*)&att[c8+4];
  uint4 du = *(const uint4*)&XWbf[(size_t)node*128 + c8];
  float xd0=BFLO(du.x), xd1=BFHI(du.x), xd2=BFLO(du.y), xd3=BFHI(du.y);
  float xd4=BFLO(du.z), xd5=BFHI(du.z), xd6=BFLO(du.w), xd7=BFHI(du.w);

  int beg = row_ptr[node], end = row_ptr[node+1];
  float s = 0.f;
  float ac0=0.f, ac1=0.f, ac2=0.f, ac3=0.f, ac4=0.f, ac5=0.f, ac6=0.f, ac7=0.f;

  for(int i = beg; i < end; i += 8){
    int e0 = i + g, e1 = i + 4 + g;
    int i0 = min(e0, end-1), i1 = min(e1, end-1);
    int s0 = csr_src[i0];
    int s1 = csr_src[i1];
    uint4 u0 = *(const uint4*)&XWbf[(size_t)s0*128 + c8];
    uint4 u1 = *(const uint4*)&XWbf[(size_t)s1*128 + c8];

    // --- edge slot e0 ---
    {
      float x0=BFLO(u0.x), x1=BFHI(u0.x), x2=BFLO(u0.y), x3=BFHI(u0.y);
      float x4=BFLO(u0.z), x5=BFHI(u0.z), x6=BFLO(u0.w), x7=BFHI(u0.w);
      float v0=xd0+x0, v1=xd1+x1, v2=xd2+x2, v3=xd3+x3;
      float v4=xd4+x4, v5=xd5+x5, v6=xd6+x6, v7=xd7+x7;
      v0 = fmaxf(v0,0.f)+0.2f*fminf(v0,0.f); v1 = fmaxf(v1,0.f)+0.2f*fminf(v1,0.f);
      v2 = fmaxf(v2,0.f)+0.2f*fminf(v2,0.f); v3 = fmaxf(v3,0.f)+0.2f*fminf(v3,0.f);
      v4 = fmaxf(v4,0.f)+0.2f*fminf(v4,0.f); v5 = fmaxf(v5,0.f)+0.2f*fminf(v5,0.f);
      v6 = fmaxf(v6,0.f)+0.2f*fminf(v6,0.f); v7 = fmaxf(v7,0.f)+0.2f*fminf(v7,0.f);
      float p = v0*a0.x + v1*a0.y + v2*a0.z + v3*a0.w
              + v4*a1.x + v5*a1.y + v6*a1.z + v7*a1.w;
      DPP_ADD(p, 0xB1);   // xor1
      DPP_ADD(p, 0x4E);   // xor2
      DPP_ADD(p, 0x141);  // xor4 (row_half_mirror; quads equal after first two)
      float ex = (e0 < end) ? __expf(fminf(p, 60.f)) : 0.f;
      s += ex;
      ac0 += ex*x0; ac1 += ex*x1; ac2 += ex*x2; ac3 += ex*x3;
      ac4 += ex*x4; ac5 += ex*x5; ac6 += ex*x6; ac7 += ex*x7;
    }
    // --- edge slot e1 ---
    {
      float x0=BFLO(u1.x), x1=BFHI(u1.x), x2=BFLO(u1.y), x3=BFHI(u1.y);
      float x4=BFLO(u1.z), x5=BFHI(u1.z), x6=BFLO(u1.w), x7=BFHI(u1.w);
      float v0=xd0+x0, v1=xd1+x1, v2=xd2+x2, v3=xd3+x3;
      float v4=xd4+x4, v5=xd5+x5, v6=xd6+x6, v7=xd7+x7;
      v0 = fmaxf(v0,0.f)+0.2f*fminf(v0,0.f); v1 = fmaxf(v1,0.f)+0.2f*fminf(v1,0.f);
      v2 = fmaxf(v2,0.f)+0.2f*fminf(v2,0.f); v3 = fmaxf(v3,0.f)+0.2f*fminf(v3,0.f);
      v4 = fmaxf(v4,0.f)+0.2f*fminf(v4,0.f); v5 = fmaxf(v5,0.f)+0.2f*fminf(v5,0.f);
      v6 = fmaxf(v6,0.f)+0.2f*fminf(v6,0.f); v7 = fmaxf(v7,0.f)+0.2f*fminf(v7,0.f);
      float p = v0*a0.x + v1*a0.y + v2*a0.z + v3*a0.w
              + v4*a1.x + v5*a1.y + v6*a1.z + v7*a1.w;
      DPP_ADD(p, 0xB1);
      DPP_ADD(p, 0x4E);
      DPP_ADD(p, 0x141);
      float ex = (e1 < end) ? __expf(fminf(p, 60.f)) : 0.f;
      s += ex;
      ac0 += ex*x0; ac1 += ex*x1; ac2 += ex*x2; ac3 += ex*x3;
      ac4 += ex*x4; ac5 += ex*x5; ac6 += ex*x6; ac7 += ex*x7;
    }
  }

  // merge 4 edge-slot groups (lanes differing in bits 4,5)
  s   += __shfl_xor(s,16);   s   += __shfl_xor(s,32);
  ac0 += __shfl_xor(ac0,16); ac0 += __shfl_xor(ac0,32);
  ac1 += __shfl_xor(ac1,16); ac1 += __shfl_xor(ac1,32);
  ac2 += __shfl_xor(ac2,16); ac2 += __shfl_xor(ac2,32);
  ac3 += __shfl_xor(ac3,16); ac3 += __shfl_xor(ac3,32);
  ac4 += __shfl_xor(ac4,16); ac4 += __shfl_xor(ac4,32);
  ac5 += __shfl_xor(ac5,16); ac5 += __shfl_xor(ac5,32);
  ac6 += __shfl_xor(ac6,16); ac6 += __shfl_xor(ac6,32);
  ac7 += __shfl_xor(ac7,16); ac7 += __shfl_xor(ac7,32);

  float inv = (s > 0.f) ? 1.f/s : 0.f;
  float o0 = fmaxf(ac0*inv,0.f), o1 = fmaxf(ac1*inv,0.f);
  float o2 = fmaxf(ac2*inv,0.f), o3 = fmaxf(ac3*inv,0.f);
  float o4 = fmaxf(ac4*inv,0.f), o5 = fmaxf(ac5*inv,0.f);
  float o6 = fmaxf(ac6*inv,0.f), o7 = fmaxf(ac7*inv,0.f);

  if(FUSE == 0){
    if(lane < 16){
      *(float4*)&outp[(size_t)node*128 + c8]     = make_float4(o0,o1,o2,o3);
      *(float4*)&outp[(size_t)node*128 + c8 + 4] = make_float4(o4,o5,o6,o7);
    }
  } else {
    float4 wf0 = *(const float4*)&wfold[c8];
    float4 wf1 = *(const float4*)&wfold[c8+4];
    float tt = o0*wf0.x + o1*wf0.y + o2*wf0.z + o3*wf0.w
             + o4*wf1.x + o5*wf1.y + o6*wf1.z + o7*wf1.w;
    DPP_ADD(tt, 0xB1);
    DPP_ADD(tt, 0x4E);
    DPP_ADD(tt, 0x141);
    DPP_ADD(tt, 0x140);  // xor8 (row_mirror; 8-groups equal after first three)
    if(lane == 0)
      outp[node] = 1.f/(1.f + __expf(-(tt + wfold[128])));
  }
}

// ================= launcher =================

static inline size_t alignup(size_t v){ return (v + 255) & ~(size_t)255; }

extern "C" void kernel_launch(void* const* d_in, const int* in_sizes, int n_in,
                              void* d_out, int out_size, void* d_ws, size_t ws_size,
                              hipStream_t stream) {
  const float* x    = (const float*)d_in[0];
  const int*   ei   = (const int*)  d_in[1];
  const float* W1   = (const float*)d_in[2];
  const float* b1   = (const float*)d_in[3];
  const float* att1 = (const float*)d_in[4];
  const float* W2   = (const float*)d_in[5];
  const float* b2   = (const float*)d_in[6];
  const float* att2 = (const float*)d_in[7];
  const float* Wp1  = (const float*)d_in[8];
  const float* bp1  = (const float*)d_in[9];
  const float* Wp2  = (const float*)d_in[10];
  const float* bp2  = (const float*)d_in[11];
  float* out = (float*)d_out;

  int N = in_sizes[0] / 128;
  int E = in_sizes[1] / 2;

  char* ws = (char*)d_ws;
  size_t off = 0;
  float* G1            = (float*)(ws + off); off = alignup(off + (size_t)N*128*sizeof(float));
  unsigned short* XWbf = (unsigned short*)(ws + off); off = alignup(off + (size_t)N*128*sizeof(unsigned short));
  int* csr_src  = (int*)(ws + off); off = alignup(off + (size_t)E*sizeof(int));
  int* slot     = (int*)(ws + off); off = alignup(off + (size_t)E*sizeof(int));
  int* row_ptr  = (int*)(ws + off); off = alignup(off + (size_t)(N+1)*sizeof(int));
  int* cnt      = (int*)(ws + off); off = alignup(off + (size_t)N*sizeof(int));
  int* bsum     = (int*)(ws + off); off = alignup(off + 64*sizeof(int));
  float* WT1    = (float*)(ws + off); off = alignup(off + 128*128*sizeof(float));
  float* WT2    = (float*)(ws + off); off = alignup(off + 128*128*sizeof(float));
  float* wfold  = (float*)(ws + off); off = alignup(off + 129*sizeof(float));

  const int* esrc = ei;
  const int* edst = ei + E;

  hipMemsetAsync(cnt, 0, (size_t)N*sizeof(int), stream);

  int nb = (N + 1023) / 1024;
  countslot_k<<<(E+255)/256, 256, 0, stream>>>(edst, cnt, slot, E);
  scan1_k<<<nb, 1024, 0, stream>>>(cnt, bsum, N);
  scan2_k<<<1, 64, 0, stream>>>(bsum, nb, row_ptr, N, E);
  scan3_k<<<nb, 1024, 0, stream>>>(cnt, bsum, row_ptr, N);
  fill2_k<<<(E+255)/256, 256, 0, stream>>>(esrc, edst, slot, row_ptr, csr_src, E);

  transpose128_k<<<16, 256, 0, stream>>>(W1, WT1);
  transpose128_k<<<16, 256, 0, stream>>>(W2, WT2);
  fold_k<<<1, 192, 0, stream>>>(Wp1, bp1, Wp2, bp2, wfold);

  int gb = (N + 63) / 64;
  // layer 1
  gemm_bf_k<<<gb, 128, 0, stream>>>(x, WT1, b1, XWbf, N);
  gat_v3_k<0><<<(N+3)/4, 256, 0, stream>>>(XWbf, att1, row_ptr, csr_src, G1, nullptr, N);
  // layer 2
  gemm_bf_k<<<gb, 128, 0, stream>>>(G1, WT2, b2, XWbf, N);
  gat_v3_k<1><<<(N+3)/4, 256, 0, stream>>>(XWbf, att2, row_ptr, csr_src, out, wfold, N);
}

// Round 6
// 207.650 us; speedup vs baseline: 1.7876x; 1.0948x over previous
//
#include <hip/hip_runtime.h>
#include <math.h>

typedef __attribute__((ext_vector_type(2))) float f32x2;

// ================= CSR build =================

__global__ void scan1_k(const int* __restrict__ cnt, int* __restrict__ bsum, int n){
  __shared__ int ws[16];
  int i = blockIdx.x*1024 + threadIdx.x;
  int v = (i < n) ? cnt[i] : 0;
  #pragma unroll
  for(int m=1;m<64;m<<=1) v += __shfl_xor(v, m);
  if((threadIdx.x & 63) == 0) ws[threadIdx.x >> 6] = v;
  __syncthreads();
  if(threadIdx.x == 0){
    int s = 0;
    #pragma unroll
    for(int w=0; w<16; w++) s += ws[w];
    bsum[blockIdx.x] = s;
  }
}

__global__ void scan2_k(int* __restrict__ bsum, int nb, int* __restrict__ row_ptr, int n, int E){
  int lane = threadIdx.x & 63;
  int v = (lane < nb) ? bsum[lane] : 0;
  int inc = v;
  #pragma unroll
  for(int off=1; off<64; off<<=1){
    int t = __shfl_up(inc, off);
    if(lane >= off) inc += t;
  }
  if(lane < nb) bsum[lane] = inc - v;
  if(lane == 0) row_ptr[n] = E;
}

__global__ void scan3_k(const int* __restrict__ cnt, const int* __restrict__ bsum,
                        int* __restrict__ row_ptr, int n){
  __shared__ int sm[1024];
  int i = blockIdx.x*1024 + threadIdx.x;
  int v = (i<n)? cnt[i] : 0;
  sm[threadIdx.x] = v;
  __syncthreads();
  for(int off=1; off<1024; off<<=1){
    int t = (threadIdx.x>=off)? sm[threadIdx.x-off] : 0;
    __syncthreads();
    sm[threadIdx.x] += t;
    __syncthreads();
  }
  if(i<n)
    row_ptr[i] = sm[threadIdx.x] - v + bsum[blockIdx.x];
}

__global__ void fill2_k(const int* __restrict__ src, const int* __restrict__ dst,
                        const int* __restrict__ slot, const int* __restrict__ row_ptr,
                        int* __restrict__ csr_src, int E){
  int e = blockIdx.x*blockDim.x + threadIdx.x;
  if(e < E)
    csr_src[row_ptr[dst[e]] + slot[e]] = src[e];
}

// ================= fused prep: countslot + transpose(W1) + transpose(W2) + fold =================

__global__ __launch_bounds__(256) void prep_k(
    const int* __restrict__ dst, int* __restrict__ cnt, int* __restrict__ slot, int E, int nEB,
    const float* __restrict__ W1, float* __restrict__ WT1,
    const float* __restrict__ W2, float* __restrict__ WT2,
    const float* __restrict__ Wp1, const float* __restrict__ bp1,
    const float* __restrict__ Wp2, const float* __restrict__ bp2,
    float* __restrict__ wfold)
{
  __shared__ float tile[32][33];
  int b = blockIdx.x;
  int t = threadIdx.x;
  if(b < nEB){
    int e = b*256 + t;
    if(e < E) slot[e] = atomicAdd(&cnt[dst[e]], 1);
    return;
  }
  int tb = b - nEB;
  if(tb < 32){
    const float* W = (tb < 16) ? W1 : W2;
    float* WT      = (tb < 16) ? WT1 : WT2;
    int bb = tb & 15;
    int tx = (bb & 3) * 32;
    int ty = (bb >> 2) * 32;
    int c = t & 31;
    int r0 = (t >> 5) * 4;
    #pragma unroll
    for(int i=0;i<4;i++)
      tile[r0+i][c] = W[(size_t)(ty + r0 + i)*128 + tx + c];
    __syncthreads();
    #pragma unroll
    for(int i=0;i<4;i++)
      WT[(size_t)(tx + r0 + i)*128 + ty + c] = tile[c][r0+i];
    return;
  }
  // fold block
  int k = t;
  if(k < 128){
    float s = 0.f;
    for(int j=0;j<64;j++) s += Wp2[j]*Wp1[(size_t)j*128 + k];
    wfold[k] = s;
  } else if(k == 128){
    float s = bp2[0];
    for(int j=0;j<64;j++) s += Wp2[j]*bp1[j];
    wfold[128] = s;
  }
}

// ================= GEMM (f32 in, bf16 out) =================

__device__ __forceinline__ unsigned pack_bf2(float lo, float hi){
  unsigned ul = __float_as_uint(lo); ul += 0x7fffu + ((ul>>16)&1u);
  unsigned uh = __float_as_uint(hi); uh += 0x7fffu + ((uh>>16)&1u);
  return (uh & 0xffff0000u) | (ul >> 16);
}

__global__ __launch_bounds__(128) void gemm_bf_k(const float* __restrict__ X,
    const float* __restrict__ WT, const float* __restrict__ b,
    unsigned short* __restrict__ Ybf, int nrows){
  __shared__ float XT[128*68];
  int t = threadIdx.x;
  int r = t >> 1;
  int kh = (t & 1) * 64;
  int row = blockIdx.x*64 + r;
  const float* xrow = &X[(size_t)min(row, nrows-1)*128];
  bool rok = row < nrows;
  #pragma unroll
  for(int q=0;q<16;q++){
    float4 v = rok ? *(const float4*)&xrow[kh + 4*q] : make_float4(0.f,0.f,0.f,0.f);
    XT[(kh+4*q+0)*68 + r] = v.x;
    XT[(kh+4*q+1)*68 + r] = v.y;
    XT[(kh+4*q+2)*68 + r] = v.z;
    XT[(kh+4*q+3)*68 + r] = v.w;
  }
  __syncthreads();

  int wv = t >> 6, lane = t & 63;
  int rg = lane >> 4, cg = lane & 15;
  int rbase = wv*32 + rg*8;
  int cbase = cg*8;

  float acc[8][8];
  #pragma unroll
  for(int i=0;i<8;i++)
    #pragma unroll
    for(int j=0;j<8;j++) acc[i][j] = 0.f;

  #pragma unroll 4
  for(int k=0;k<128;k++){
    float4 x0 = *(const float4*)&XT[k*68 + rbase];
    float4 x1 = *(const float4*)&XT[k*68 + rbase + 4];
    float4 w0 = *(const float4*)&WT[(size_t)k*128 + cbase];
    float4 w1 = *(const float4*)&WT[(size_t)k*128 + cbase + 4];
    float xs[8] = {x0.x,x0.y,x0.z,x0.w,x1.x,x1.y,x1.z,x1.w};
    float wsv[8] = {w0.x,w0.y,w0.z,w0.w,w1.x,w1.y,w1.z,w1.w};
    #pragma unroll
    for(int i=0;i<8;i++)
      #pragma unroll
      for(int j=0;j<8;j++)
        acc[i][j] += xs[i]*wsv[j];
  }

  float4 bb0 = *(const float4*)&b[cbase];
  float4 bb1 = *(const float4*)&b[cbase+4];
  float bs[8] = {bb0.x,bb0.y,bb0.z,bb0.w,bb1.x,bb1.y,bb1.z,bb1.w};

  #pragma unroll
  for(int i=0;i<8;i++){
    int orow = blockIdx.x*64 + rbase + i;
    if(orow < nrows){
      uint4 o;
      o.x = pack_bf2(acc[i][0]+bs[0], acc[i][1]+bs[1]);
      o.y = pack_bf2(acc[i][2]+bs[2], acc[i][3]+bs[3]);
      o.z = pack_bf2(acc[i][4]+bs[4], acc[i][5]+bs[5]);
      o.w = pack_bf2(acc[i][6]+bs[6], acc[i][7]+bs[7]);
      *(uint4*)&Ybf[(size_t)orow*128 + cbase] = o;
    }
  }
}

// ================= GATv2 edge phase v4 (stride-fixed) =================
// wave/node; 16 lanes/edge (4 slots g=lane>>4), lane owns 8 channels as 4 f32x2 pairs.
// Row = 128 bf16 = 16 uint4  ->  XW4[node*16 + cg].   (v5 bug: used *8.)

#define BFLO(u) __uint_as_float((u)<<16)
#define BFHI(u) __uint_as_float((u)&0xffff0000u)
#define DPP_ADD(v, ctrl) { int _t = __builtin_amdgcn_update_dpp(0, __float_as_int(v), ctrl, 0xF, 0xF, true); (v) += __int_as_float(_t); }

template<int FUSE>
__global__ __launch_bounds__(256) void gat_v4_k(
    const unsigned short* __restrict__ XWbf,
    const float* __restrict__ att,
    const int* __restrict__ row_ptr, const int* __restrict__ csr_src,
    float* __restrict__ outp, const float* __restrict__ wfold, int n)
{
  int wid = threadIdx.x >> 6, lane = threadIdx.x & 63;
  int node = blockIdx.x*4 + wid;
  if(node >= n) return;
  int g = lane >> 4;
  int cg = lane & 15;
  int c8 = cg * 8;

  float4 A0 = *(const float4*)&att[c8];
  float4 A1 = *(const float4*)&att[c8+4];
  f32x2 a[4] = { {A0.x,A0.y}, {A0.z,A0.w}, {A1.x,A1.y}, {A1.z,A1.w} };

  const uint4* XW4 = (const uint4*)XWbf;     // row = 16 uint4
  uint4 du = XW4[node*16 + cg];
  f32x2 xd[4] = { {BFLO(du.x),BFHI(du.x)}, {BFLO(du.y),BFHI(du.y)},
                  {BFLO(du.z),BFHI(du.z)}, {BFLO(du.w),BFHI(du.w)} };

  int beg = row_ptr[node], end = row_ptr[node+1];
  float s = 0.f;
  f32x2 acc[4] = {{0.f,0.f},{0.f,0.f},{0.f,0.f},{0.f,0.f}};

  if(end > beg){
    int sn_cur = csr_src[min(beg + g, end-1)];
    int sn_nxt = (beg+4 < end) ? csr_src[min(beg+4 + g, end-1)] : sn_cur;
    uint4 u = XW4[sn_cur*16 + cg];
    for(int i = beg; i < end; i += 4){
      uint4 u_nxt = XW4[sn_nxt*16 + cg];                      // prefetch row (dup-safe)
      int sn_nn = (i+8 < end) ? csr_src[min(i+8 + g, end-1)] : sn_nxt;  // csr 2 ahead
      bool ok = (i + g) < end;

      f32x2 x0 = {BFLO(u.x), BFHI(u.x)};
      f32x2 x1 = {BFLO(u.y), BFHI(u.y)};
      f32x2 x2 = {BFLO(u.z), BFHI(u.z)};
      f32x2 x3 = {BFLO(u.w), BFHI(u.w)};
      f32x2 v0 = xd[0]+x0, v1 = xd[1]+x1, v2 = xd[2]+x2, v3 = xd[3]+x3;
      f32x2 q0 = v0*0.2f, q1 = v1*0.2f, q2 = v2*0.2f, q3 = v3*0.2f;
      f32x2 l0, l1, l2, l3;
      l0.x = fmaxf(v0.x,q0.x); l0.y = fmaxf(v0.y,q0.y);
      l1.x = fmaxf(v1.x,q1.x); l1.y = fmaxf(v1.y,q1.y);
      l2.x = fmaxf(v2.x,q2.x); l2.y = fmaxf(v2.y,q2.y);
      l3.x = fmaxf(v3.x,q3.x); l3.y = fmaxf(v3.y,q3.y);
      f32x2 p2 = l0*a[0];
      p2 += l1*a[1];
      p2 += l2*a[2];
      p2 += l3*a[3];
      float p = p2.x + p2.y;
      DPP_ADD(p, 0xB1);   // xor1
      DPP_ADD(p, 0x4E);   // xor2
      DPP_ADD(p, 0x141);  // half-mirror (8-lane head group complete)
      float ex = ok ? __expf(fminf(p, 60.f)) : 0.f;
      s += ex;
      f32x2 e2 = {ex, ex};
      acc[0] += e2*x0;
      acc[1] += e2*x1;
      acc[2] += e2*x2;
      acc[3] += e2*x3;

      u = u_nxt; sn_nxt = sn_nn;
    }
  }

  // merge the 4 edge-slot groups (xor lanes by 16, 32)
  s += __shfl_xor(s,16);  s += __shfl_xor(s,32);
  #pragma unroll
  for(int j=0;j<4;j++){
    acc[j].x += __shfl_xor(acc[j].x,16); acc[j].x += __shfl_xor(acc[j].x,32);
    acc[j].y += __shfl_xor(acc[j].y,16); acc[j].y += __shfl_xor(acc[j].y,32);
  }

  float inv = (s > 0.f) ? 1.f/s : 0.f;
  f32x2 o[4];
  #pragma unroll
  for(int j=0;j<4;j++){
    o[j].x = fmaxf(acc[j].x*inv, 0.f);
    o[j].y = fmaxf(acc[j].y*inv, 0.f);
  }

  if(FUSE == 0){
    if(lane < 16){
      *(float4*)&outp[(size_t)node*128 + c8]     = make_float4(o[0].x,o[0].y,o[1].x,o[1].y);
      *(float4*)&outp[(size_t)node*128 + c8 + 4] = make_float4(o[2].x,o[2].y,o[3].x,o[3].y);
    }
  } else {
    float4 wf0 = *(const float4*)&wfold[c8];
    float4 wf1 = *(const float4*)&wfold[c8+4];
    float tt = o[0].x*wf0.x + o[0].y*wf0.y + o[1].x*wf0.z + o[1].y*wf0.w
             + o[2].x*wf1.x + o[2].y*wf1.y + o[3].x*wf1.z + o[3].y*wf1.w;
    DPP_ADD(tt, 0xB1);
    DPP_ADD(tt, 0x4E);
    DPP_ADD(tt, 0x141);
    DPP_ADD(tt, 0x140);  // row-mirror (16-lane group complete)
    if(lane == 0)
      outp[node] = 1.f/(1.f + __expf(-(tt + wfold[128])));
  }
}

// ================= launcher =================

static inline size_t alignup(size_t v){ return (v + 255) & ~(size_t)255; }

extern "C" void kernel_launch(void* const* d_in, const int* in_sizes, int n_in,
                              void* d_out, int out_size, void* d_ws, size_t ws_size,
                              hipStream_t stream) {
  const float* x    = (const float*)d_in[0];
  const int*   ei   = (const int*)  d_in[1];
  const float* W1   = (const float*)d_in[2];
  const float* b1   = (const float*)d_in[3];
  const float* att1 = (const float*)d_in[4];
  const float* W2   = (const float*)d_in[5];
  const float* b2   = (const float*)d_in[6];
  const float* att2 = (const float*)d_in[7];
  const float* Wp1  = (const float*)d_in[8];
  const float* bp1  = (const float*)d_in[9];
  const float* Wp2  = (const float*)d_in[10];
  const float* bp2  = (const float*)d_in[11];
  float* out = (float*)d_out;

  int N = in_sizes[0] / 128;
  int E = in_sizes[1] / 2;

  char* ws = (char*)d_ws;
  size_t off = 0;
  float* G1            = (float*)(ws + off); off = alignup(off + (size_t)N*128*sizeof(float));
  unsigned short* XWbf = (unsigned short*)(ws + off); off = alignup(off + (size_t)N*128*sizeof(unsigned short));
  int* csr_src  = (int*)(ws + off); off = alignup(off + (size_t)E*sizeof(int));
  int* slot     = (int*)(ws + off); off = alignup(off + (size_t)E*sizeof(int));
  int* row_ptr  = (int*)(ws + off); off = alignup(off + (size_t)(N+1)*sizeof(int));
  int* cnt      = (int*)(ws + off); off = alignup(off + (size_t)N*sizeof(int));
  int* bsum     = (int*)(ws + off); off = alignup(off + 64*sizeof(int));
  float* WT1    = (float*)(ws + off); off = alignup(off + 128*128*sizeof(float));
  float* WT2    = (float*)(ws + off); off = alignup(off + 128*128*sizeof(float));
  float* wfold  = (float*)(ws + off); off = alignup(off + 129*sizeof(float));

  const int* esrc = ei;
  const int* edst = ei + E;

  hipMemsetAsync(cnt, 0, (size_t)N*sizeof(int), stream);

  int nEB = (E + 255) / 256;
  int nb = (N + 1023) / 1024;
  prep_k<<<nEB + 33, 256, 0, stream>>>(edst, cnt, slot, E, nEB,
                                       W1, WT1, W2, WT2, Wp1, bp1, Wp2, bp2, wfold);
  scan1_k<<<nb, 1024, 0, stream>>>(cnt, bsum, N);
  scan2_k<<<1, 64, 0, stream>>>(bsum, nb, row_ptr, N, E);
  scan3_k<<<nb, 1024, 0, stream>>>(cnt, bsum, row_ptr, N);
  fill2_k<<<(E+255)/256, 256, 0, stream>>>(esrc, edst, slot, row_ptr, csr_src, E);

  int gb = (N + 63) / 64;
  // layer 1
  gemm_bf_k<<<gb, 128, 0, stream>>>(x, WT1, b1, XWbf, N);
  gat_v4_k<0><<<(N+3)/4, 256, 0, stream>>>(XWbf, att1, row_ptr, csr_src, G1, nullptr, N);
  // layer 2
  gemm_bf_k<<<gb, 128, 0, stream>>>(G1, WT2, b2, XWbf, N);
  gat_v4_k<1><<<(N+3)/4, 256, 0, stream>>>(XWbf, att2, row_ptr, csr_src, out, wfold, N);
}

// Round 7
// 162.337 us; speedup vs baseline: 2.2865x; 1.2791x over previous
//
#include <hip/hip_runtime.h>
#include <math.h>

typedef __attribute__((ext_vector_type(2))) float f32x2;
typedef __attribute__((ext_vector_type(4))) float fx4;
typedef __attribute__((ext_vector_type(8))) short s16x8;

// ================= CSR build =================

__global__ void scan1_k(const int* __restrict__ cnt, int* __restrict__ bsum, int n){
  __shared__ int ws[16];
  int i = blockIdx.x*1024 + threadIdx.x;
  int v = (i < n) ? cnt[i] : 0;
  #pragma unroll
  for(int m=1;m<64;m<<=1) v += __shfl_xor(v, m);
  if((threadIdx.x & 63) == 0) ws[threadIdx.x >> 6] = v;
  __syncthreads();
  if(threadIdx.x == 0){
    int s = 0;
    #pragma unroll
    for(int w=0; w<16; w++) s += ws[w];
    bsum[blockIdx.x] = s;
  }
}

__global__ void scan2_k(int* __restrict__ bsum, int nb, int* __restrict__ row_ptr, int n, int E){
  int lane = threadIdx.x & 63;
  int v = (lane < nb) ? bsum[lane] : 0;
  int inc = v;
  #pragma unroll
  for(int off=1; off<64; off<<=1){
    int t = __shfl_up(inc, off);
    if(lane >= off) inc += t;
  }
  if(lane < nb) bsum[lane] = inc - v;
  if(lane == 0) row_ptr[n] = E;
}

__global__ void scan3_k(const int* __restrict__ cnt, const int* __restrict__ bsum,
                        int* __restrict__ row_ptr, int n){
  __shared__ int sm[1024];
  int i = blockIdx.x*1024 + threadIdx.x;
  int v = (i<n)? cnt[i] : 0;
  sm[threadIdx.x] = v;
  __syncthreads();
  for(int off=1; off<1024; off<<=1){
    int t = (threadIdx.x>=off)? sm[threadIdx.x-off] : 0;
    __syncthreads();
    sm[threadIdx.x] += t;
    __syncthreads();
  }
  if(i<n)
    row_ptr[i] = sm[threadIdx.x] - v + bsum[blockIdx.x];
}

__global__ void fill2_k(const int* __restrict__ src, const int* __restrict__ dst,
                        const int* __restrict__ slot, const int* __restrict__ row_ptr,
                        int* __restrict__ csr_src, int E){
  int e = blockIdx.x*blockDim.x + threadIdx.x;
  if(e < E)
    csr_src[row_ptr[dst[e]] + slot[e]] = src[e];
}

// ================= bf16 helpers =================

__device__ __forceinline__ unsigned pack_bf2(float lo, float hi){
  unsigned ul = __float_as_uint(lo); ul += 0x7fffu + ((ul>>16)&1u);
  unsigned uh = __float_as_uint(hi); uh += 0x7fffu + ((uh>>16)&1u);
  return (uh & 0xffff0000u) | (ul >> 16);
}

// ================= fused prep: countslot + W1/W2 -> bf16 + fold =================

__global__ __launch_bounds__(256) void prep_k(
    const int* __restrict__ dst, int* __restrict__ cnt, int* __restrict__ slot, int E, int nEB,
    const float* __restrict__ W1, unsigned short* __restrict__ W1bf,
    const float* __restrict__ W2, unsigned short* __restrict__ W2bf,
    const float* __restrict__ Wp1, const float* __restrict__ bp1,
    const float* __restrict__ Wp2, const float* __restrict__ bp2,
    float* __restrict__ wfold)
{
  int b = blockIdx.x;
  int t = threadIdx.x;
  if(b < nEB){
    int e = b*256 + t;
    if(e < E) slot[e] = atomicAdd(&cnt[dst[e]], 1);
    return;
  }
  int tb = b - nEB;
  if(tb < 2){
    const float4* Ws = (const float4*)((tb==0)? W1 : W2);
    uint2* Wd = (uint2*)((tb==0)? W1bf : W2bf);
    #pragma unroll
    for(int i=0;i<16;i++){
      int idx = t + i*256;            // 4096 float4 = 16384 floats
      float4 v = Ws[idx];
      uint2 o; o.x = pack_bf2(v.x, v.y); o.y = pack_bf2(v.z, v.w);
      Wd[idx] = o;
    }
    return;
  }
  // fold block
  int k = t;
  if(k < 128){
    float s = 0.f;
    for(int j=0;j<64;j++) s += Wp2[j]*Wp1[(size_t)j*128 + k];
    wfold[k] = s;
  } else if(k == 128){
    float s = bp2[0];
    for(int j=0;j<64;j++) s += Wp2[j]*bp1[j];
    wfold[128] = s;
  }
}

// ================= GEMM v2: MFMA bf16, split-hi/lo X for f32-grade accuracy =================
// Y[r][j] = sum_k X[r][k]*W[j][k] + b[j], output bf16.
// Block 256 thr = 4 waves, 64 rows. W (bf16 [j][k]) staged in LDS, XOR-swizzled in
// 16B chunks (chunk ^= row&15) to break the stride-256B 16-way bank conflict.
// A-frags read straight from global (per-instruction: 16 full cache lines, coalesced).
// X split: x = hi + lo (bf16 each); acc += hi*W + lo*W  => error ~ W-quant only.

__global__ __launch_bounds__(256) void gemm_mfma_k(
    const float* __restrict__ X, const unsigned short* __restrict__ Wbf,
    const float* __restrict__ b, unsigned short* __restrict__ Ybf, int nrows)
{
  __shared__ uint4 Wl[128*16];   // 32KB, [row][chunk ^ (row&15)]
  int t = threadIdx.x;
  {
    const uint4* Ws = (const uint4*)Wbf;
    #pragma unroll
    for(int i=0;i<8;i++){
      int idx = t + i*256;         // 2048 chunks
      int row = idx >> 4, ch = idx & 15;
      Wl[(row<<4) | (ch ^ (row & 15))] = Ws[idx];
    }
  }
  __syncthreads();

  int wv = t >> 6, lane = t & 63;
  int r = lane & 15, kb = lane >> 4;
  int row = blockIdx.x*64 + wv*16 + r;
  const float* xrow = &X[(size_t)min(row, nrows-1)*128];

  fx4 acc[8];
  #pragma unroll
  for(int c=0;c<8;c++) acc[c] = (fx4){0.f,0.f,0.f,0.f};

  #pragma unroll
  for(int kt=0;kt<4;kt++){
    int k0 = kt*32 + kb*8;
    float4 v0 = *(const float4*)&xrow[k0];
    float4 v1 = *(const float4*)&xrow[k0+4];
    float vs[8] = {v0.x,v0.y,v0.z,v0.w,v1.x,v1.y,v1.z,v1.w};
    s16x8 ahi, alo;
    #pragma unroll
    for(int j=0;j<8;j++){
      unsigned u = __float_as_uint(vs[j]);
      unsigned uh = u + 0x7fffu + ((u>>16)&1u);
      unsigned short h = (unsigned short)(uh >> 16);
      float hf = __uint_as_float(((unsigned)h)<<16);
      float lo = vs[j] - hf;
      unsigned ul = __float_as_uint(lo);
      ul += 0x7fffu + ((ul>>16)&1u);
      ahi[j] = (short)h;
      alo[j] = (short)(ul>>16);
    }
    int chunk = kt*4 + kb;
    #pragma unroll
    for(int c=0;c<8;c++){
      uint4 wb = Wl[((c*16 + r)<<4) | (chunk ^ r)];
      s16x8 bb = *(s16x8*)&wb;
      acc[c] = __builtin_amdgcn_mfma_f32_16x16x32_bf16(ahi, bb, acc[c], 0,0,0);
      acc[c] = __builtin_amdgcn_mfma_f32_16x16x32_bf16(alo, bb, acc[c], 0,0,0);
    }
  }

  // D layout: col = lane&15, row = (lane>>4)*4 + reg
  int orow0 = blockIdx.x*64 + wv*16 + (lane>>4)*4;
  int colb = lane & 15;
  #pragma unroll
  for(int c=0;c<8;c++){
    int col = c*16 + colb;
    float bias = b[col];
    #pragma unroll
    for(int q=0;q<4;q++){
      int orow = orow0 + q;
      if(orow < nrows){
        unsigned u = __float_as_uint(acc[c][q] + bias);
        u += 0x7fffu + ((u>>16)&1u);
        Ybf[(size_t)orow*128 + col] = (unsigned short)(u>>16);
      }
    }
  }
}

// ================= GATv2 edge phase v4 =================

#define BFLO(u) __uint_as_float((u)<<16)
#define BFHI(u) __uint_as_float((u)&0xffff0000u)
#define DPP_ADD(v, ctrl) { int _t = __builtin_amdgcn_update_dpp(0, __float_as_int(v), ctrl, 0xF, 0xF, true); (v) += __int_as_float(_t); }

template<int FUSE>
__global__ __launch_bounds__(256) void gat_v4_k(
    const unsigned short* __restrict__ XWbf,
    const float* __restrict__ att,
    const int* __restrict__ row_ptr, const int* __restrict__ csr_src,
    float* __restrict__ outp, const float* __restrict__ wfold, int n)
{
  int wid = threadIdx.x >> 6, lane = threadIdx.x & 63;
  int node = blockIdx.x*4 + wid;
  if(node >= n) return;
  int g = lane >> 4;
  int cg = lane & 15;
  int c8 = cg * 8;

  float4 A0 = *(const float4*)&att[c8];
  float4 A1 = *(const float4*)&att[c8+4];
  f32x2 a[4] = { {A0.x,A0.y}, {A0.z,A0.w}, {A1.x,A1.y}, {A1.z,A1.w} };

  const uint4* XW4 = (const uint4*)XWbf;     // row = 16 uint4
  uint4 du = XW4[node*16 + cg];
  f32x2 xd[4] = { {BFLO(du.x),BFHI(du.x)}, {BFLO(du.y),BFHI(du.y)},
                  {BFLO(du.z),BFHI(du.z)}, {BFLO(du.w),BFHI(du.w)} };

  int beg = row_ptr[node], end = row_ptr[node+1];
  float s = 0.f;
  f32x2 acc[4] = {{0.f,0.f},{0.f,0.f},{0.f,0.f},{0.f,0.f}};

  if(end > beg){
    int sn_cur = csr_src[min(beg + g, end-1)];
    int sn_nxt = (beg+4 < end) ? csr_src[min(beg+4 + g, end-1)] : sn_cur;
    uint4 u = XW4[sn_cur*16 + cg];
    for(int i = beg; i < end; i += 4){
      uint4 u_nxt = XW4[sn_nxt*16 + cg];
      int sn_nn = (i+8 < end) ? csr_src[min(i+8 + g, end-1)] : sn_nxt;
      bool ok = (i + g) < end;

      f32x2 x0 = {BFLO(u.x), BFHI(u.x)};
      f32x2 x1 = {BFLO(u.y), BFHI(u.y)};
      f32x2 x2 = {BFLO(u.z), BFHI(u.z)};
      f32x2 x3 = {BFLO(u.w), BFHI(u.w)};
      f32x2 v0 = xd[0]+x0, v1 = xd[1]+x1, v2 = xd[2]+x2, v3 = xd[3]+x3;
      f32x2 q0 = v0*0.2f, q1 = v1*0.2f, q2 = v2*0.2f, q3 = v3*0.2f;
      f32x2 l0, l1, l2, l3;
      l0.x = fmaxf(v0.x,q0.x); l0.y = fmaxf(v0.y,q0.y);
      l1.x = fmaxf(v1.x,q1.x); l1.y = fmaxf(v1.y,q1.y);
      l2.x = fmaxf(v2.x,q2.x); l2.y = fmaxf(v2.y,q2.y);
      l3.x = fmaxf(v3.x,q3.x); l3.y = fmaxf(v3.y,q3.y);
      f32x2 p2 = l0*a[0];
      p2 += l1*a[1];
      p2 += l2*a[2];
      p2 += l3*a[3];
      float p = p2.x + p2.y;
      DPP_ADD(p, 0xB1);   // xor1
      DPP_ADD(p, 0x4E);   // xor2
      DPP_ADD(p, 0x141);  // half-mirror (8-lane head group complete)
      float ex = ok ? __expf(fminf(p, 60.f)) : 0.f;
      s += ex;
      f32x2 e2 = {ex, ex};
      acc[0] += e2*x0;
      acc[1] += e2*x1;
      acc[2] += e2*x2;
      acc[3] += e2*x3;

      u = u_nxt; sn_nxt = sn_nn;
    }
  }

  s += __shfl_xor(s,16);  s += __shfl_xor(s,32);
  #pragma unroll
  for(int j=0;j<4;j++){
    acc[j].x += __shfl_xor(acc[j].x,16); acc[j].x += __shfl_xor(acc[j].x,32);
    acc[j].y += __shfl_xor(acc[j].y,16); acc[j].y += __shfl_xor(acc[j].y,32);
  }

  float inv = (s > 0.f) ? 1.f/s : 0.f;
  f32x2 o[4];
  #pragma unroll
  for(int j=0;j<4;j++){
    o[j].x = fmaxf(acc[j].x*inv, 0.f);
    o[j].y = fmaxf(acc[j].y*inv, 0.f);
  }

  if(FUSE == 0){
    if(lane < 16){
      *(float4*)&outp[(size_t)node*128 + c8]     = make_float4(o[0].x,o[0].y,o[1].x,o[1].y);
      *(float4*)&outp[(size_t)node*128 + c8 + 4] = make_float4(o[2].x,o[2].y,o[3].x,o[3].y);
    }
  } else {
    float4 wf0 = *(const float4*)&wfold[c8];
    float4 wf1 = *(const float4*)&wfold[c8+4];
    float tt = o[0].x*wf0.x + o[0].y*wf0.y + o[1].x*wf0.z + o[1].y*wf0.w
             + o[2].x*wf1.x + o[2].y*wf1.y + o[3].x*wf1.z + o[3].y*wf1.w;
    DPP_ADD(tt, 0xB1);
    DPP_ADD(tt, 0x4E);
    DPP_ADD(tt, 0x141);
    DPP_ADD(tt, 0x140);
    if(lane == 0)
      outp[node] = 1.f/(1.f + __expf(-(tt + wfold[128])));
  }
}

// ================= launcher =================

static inline size_t alignup(size_t v){ return (v + 255) & ~(size_t)255; }

extern "C" void kernel_launch(void* const* d_in, const int* in_sizes, int n_in,
                              void* d_out, int out_size, void* d_ws, size_t ws_size,
                              hipStream_t stream) {
  const float* x    = (const float*)d_in[0];
  const int*   ei   = (const int*)  d_in[1];
  const float* W1   = (const float*)d_in[2];
  const float* b1   = (const float*)d_in[3];
  const float* att1 = (const float*)d_in[4];
  const float* W2   = (const float*)d_in[5];
  const float* b2   = (const float*)d_in[6];
  const float* att2 = (const float*)d_in[7];
  const float* Wp1  = (const float*)d_in[8];
  const float* bp1  = (const float*)d_in[9];
  const float* Wp2  = (const float*)d_in[10];
  const float* bp2  = (const float*)d_in[11];
  float* out = (float*)d_out;

  int N = in_sizes[0] / 128;
  int E = in_sizes[1] / 2;

  char* ws = (char*)d_ws;
  size_t off = 0;
  float* G1            = (float*)(ws + off); off = alignup(off + (size_t)N*128*sizeof(float));
  unsigned short* XWbf = (unsigned short*)(ws + off); off = alignup(off + (size_t)N*128*sizeof(unsigned short));
  int* csr_src  = (int*)(ws + off); off = alignup(off + (size_t)E*sizeof(int));
  int* slot     = (int*)(ws + off); off = alignup(off + (size_t)E*sizeof(int));
  int* row_ptr  = (int*)(ws + off); off = alignup(off + (size_t)(N+1)*sizeof(int));
  int* cnt      = (int*)(ws + off); off = alignup(off + (size_t)N*sizeof(int));
  int* bsum     = (int*)(ws + off); off = alignup(off + 64*sizeof(int));
  unsigned short* W1bf = (unsigned short*)(ws + off); off = alignup(off + 128*128*sizeof(unsigned short));
  unsigned short* W2bf = (unsigned short*)(ws + off); off = alignup(off + 128*128*sizeof(unsigned short));
  float* wfold  = (float*)(ws + off); off = alignup(off + 129*sizeof(float));

  const int* esrc = ei;
  const int* edst = ei + E;

  hipMemsetAsync(cnt, 0, (size_t)N*sizeof(int), stream);

  int nEB = (E + 255) / 256;
  int nb = (N + 1023) / 1024;
  prep_k<<<nEB + 3, 256, 0, stream>>>(edst, cnt, slot, E, nEB,
                                      W1, W1bf, W2, W2bf, Wp1, bp1, Wp2, bp2, wfold);
  scan1_k<<<nb, 1024, 0, stream>>>(cnt, bsum, N);
  scan2_k<<<1, 64, 0, stream>>>(bsum, nb, row_ptr, N, E);
  scan3_k<<<nb, 1024, 0, stream>>>(cnt, bsum, row_ptr, N);
  fill2_k<<<(E+255)/256, 256, 0, stream>>>(esrc, edst, slot, row_ptr, csr_src, E);

  int gb = (N + 63) / 64;
  // layer 1
  gemm_mfma_k<<<gb, 256, 0, stream>>>(x, W1bf, b1, XWbf, N);
  gat_v4_k<0><<<(N+3)/4, 256, 0, stream>>>(XWbf, att1, row_ptr, csr_src, G1, nullptr, N);
  // layer 2
  gemm_mfma_k<<<gb, 256, 0, stream>>>(G1, W2bf, b2, XWbf, N);
  gat_v4_k<1><<<(N+3)/4, 256, 0, stream>>>(XWbf, att2, row_ptr, csr_src, out, wfold, N);
}